// Round 1
// baseline (485.169 us; speedup 1.0000x reference)
//
#include <hip/hip_runtime.h>
#include <hip/hip_bf16.h>

#define N_NODES 50000
#define N_EDGES 800000

typedef unsigned short u16;
typedef short v8s __attribute__((ext_vector_type(8)));
typedef float v4f __attribute__((ext_vector_type(4)));

__device__ __forceinline__ u16 f2bf(float f){
  union { float f; unsigned u; } x; x.f = f;
  unsigned u = x.u;
  return (u16)((u + 0x7FFFu + ((u >> 16) & 1u)) >> 16);   // RNE
}
__device__ __forceinline__ float bf2f(u16 s){
  union { unsigned u; float f; } x; x.u = ((unsigned)s) << 16; return x.f;
}

// ---------------- CSR build ----------------

__global__ void k_zero(int* __restrict__ p, int n){
  int i = blockIdx.x * 256 + threadIdx.x;
  if (i < n) p[i] = 0;
}

__global__ void k_count(const int* __restrict__ edges, int* __restrict__ deg){
  int j = blockIdx.x * 256 + threadIdx.x;
  if (j < N_EDGES) atomicAdd(&deg[edges[N_EDGES + j]], 1);
}

__global__ void k_scan_blocks(const int* __restrict__ deg, int* __restrict__ off,
                              int* __restrict__ bsum){
  __shared__ int s[256];
  int tid = threadIdx.x;
  int i = blockIdx.x * 256 + tid;
  int v = (i < N_NODES) ? deg[i] : 0;
  s[tid] = v; __syncthreads();
  for (int d = 1; d < 256; d <<= 1){
    int t = (tid >= d) ? s[tid - d] : 0;
    __syncthreads();
    s[tid] += t;
    __syncthreads();
  }
  if (i < N_NODES) off[i] = s[tid] - v;          // block-local exclusive
  if (tid == 255) bsum[blockIdx.x] = s[tid];     // block total
}

__global__ void k_scan_tops(const int* __restrict__ bsum, int* __restrict__ bofs, int nb){
  __shared__ int s[256];
  int tid = threadIdx.x;
  int v = (tid < nb) ? bsum[tid] : 0;
  s[tid] = v; __syncthreads();
  for (int d = 1; d < 256; d <<= 1){
    int t = (tid >= d) ? s[tid - d] : 0;
    __syncthreads();
    s[tid] += t;
    __syncthreads();
  }
  if (tid < nb) bofs[tid] = s[tid] - v;          // exclusive over blocks
}

__global__ void k_scan_add(int* __restrict__ off, const int* __restrict__ bofs,
                           const int* __restrict__ deg, int* __restrict__ cursor,
                           float* __restrict__ invdeg){
  int i = blockIdx.x * 256 + threadIdx.x;
  if (i < N_NODES){
    int o = off[i] + bofs[blockIdx.x];
    off[i] = o;
    cursor[i] = o;
    int d = deg[i];
    invdeg[i] = 1.0f / (float)(d > 1 ? d : 1);
  }
}

__global__ void k_scatter(const int* __restrict__ edges, int* __restrict__ cursor,
                          int* __restrict__ cols){
  int j = blockIdx.x * 256 + threadIdx.x;
  if (j < N_EDGES){
    int dst = edges[N_EDGES + j];
    int pos = atomicAdd(&cursor[dst], 1);
    cols[pos] = edges[j];
  }
}

// ---------------- fp32 -> bf16 cast of x ----------------

__global__ void k_cast(const float* __restrict__ x, u16* __restrict__ Xb){
  int i = blockIdx.x * 256 + threadIdx.x;      // one per 4 floats
  if (i * 4 < N_NODES * 128){
    float4 v = ((const float4*)x)[i];
    ((ushort4*)Xb)[i] = make_ushort4(f2bf(v.x), f2bf(v.y), f2bf(v.z), f2bf(v.w));
  }
}

// ---------------- weight prep: WT[n][k] = [Wl|Wr]^T, bf16 ----------------

__global__ void k_wprep(const float* __restrict__ Wl, const float* __restrict__ Wr,
                        u16* __restrict__ WT, int N1){
  int idx = blockIdx.x * 256 + threadIdx.x;    // over (2*N1)*128
  int N = 2 * N1;
  if (idx < N * 128){
    int n = idx >> 7, k = idx & 127;
    float v = (n < N1) ? Wl[k * N1 + n] : Wr[k * N1 + (n - N1)];
    WT[n * 128 + k] = f2bf(v);
  }
}

// ---------------- fused GEMM: XL = A@Wl + b (fp32), XR = A@Wr (bf16) ----------------
// A: [M x 128] bf16 row-major.  WT: [2*N1 x 128] bf16 row-major (B^T form).
// grid.x over M/64, grid.y over (2*N1)/64.

__global__ __launch_bounds__(256) void k_gemm(const u16* __restrict__ A,
                                              const u16* __restrict__ WT,
                                              const float* __restrict__ bias,
                                              float* __restrict__ XL,
                                              u16* __restrict__ XR, int N1){
  __shared__ u16 As[64 * 136];   // +8 pad per row, 16B-aligned rows (272 B)
  __shared__ u16 Bs[64 * 136];
  const int tid = threadIdx.x;
  const int rowBase = blockIdx.x * 64;
  const int colBase = blockIdx.y * 64;

  // stage A tile (64x128) and WT tile (64x128) as 16B chunks
  #pragma unroll
  for (int it = 0; it < 4; ++it){
    int chunk = tid + it * 256;          // 0..1023
    int r = chunk >> 4, cseg = chunk & 15;
    int gr = rowBase + r;
    uint4 va = make_uint4(0u, 0u, 0u, 0u);
    if (gr < N_NODES) va = ((const uint4*)(A + (size_t)gr * 128))[cseg];
    ((uint4*)As)[r * 17 + cseg] = va;
    uint4 vb = ((const uint4*)(WT + (size_t)(colBase + r) * 128))[cseg];
    ((uint4*)Bs)[r * 17 + cseg] = vb;
  }
  __syncthreads();

  const int lane = tid & 63, wave = tid >> 6;
  const int quad = lane >> 4, l15 = lane & 15;
  const int wm = wave & 1, wn = wave >> 1;

  v4f acc[2][2] = {};
  #pragma unroll
  for (int kt = 0; kt < 4; ++kt){
    int ko = kt * 32 + quad * 8;
    v8s a0 = *(const v8s*)&As[(wm * 32 + l15) * 136 + ko];
    v8s a1 = *(const v8s*)&As[(wm * 32 + 16 + l15) * 136 + ko];
    v8s b0 = *(const v8s*)&Bs[(wn * 32 + l15) * 136 + ko];
    v8s b1 = *(const v8s*)&Bs[(wn * 32 + 16 + l15) * 136 + ko];
    acc[0][0] = __builtin_amdgcn_mfma_f32_16x16x32_bf16(a0, b0, acc[0][0], 0, 0, 0);
    acc[0][1] = __builtin_amdgcn_mfma_f32_16x16x32_bf16(a0, b1, acc[0][1], 0, 0, 0);
    acc[1][0] = __builtin_amdgcn_mfma_f32_16x16x32_bf16(a1, b0, acc[1][0], 0, 0, 0);
    acc[1][1] = __builtin_amdgcn_mfma_f32_16x16x32_bf16(a1, b1, acc[1][1], 0, 0, 0);
  }

  // epilogue: C/D layout col = lane&15, row = quad*4 + reg
  #pragma unroll
  for (int mi = 0; mi < 2; ++mi)
    #pragma unroll
    for (int ni = 0; ni < 2; ++ni)
      #pragma unroll
      for (int r = 0; r < 4; ++r){
        int grow = rowBase + wm * 32 + mi * 16 + quad * 4 + r;
        int gcol = colBase + wn * 32 + ni * 16 + l15;
        if (grow < N_NODES){
          float v = acc[mi][ni][r];
          if (gcol < N1) XL[(size_t)grow * N1 + gcol] = v + bias[gcol];
          else           XR[(size_t)grow * N1 + (gcol - N1)] = f2bf(v);
        }
      }
}

// ---------------- aggregate + combine (+ReLU, +cast) ----------------
// one wave per node; FW = feature width of this layer's outputs (128 or 64)

template<int FW, bool RELU, bool BF16OUT>
__global__ __launch_bounds__(256) void k_agg(const int* __restrict__ off,
                                             const int* __restrict__ deg,
                                             const float* __restrict__ invdeg,
                                             const int* __restrict__ cols,
                                             const float* __restrict__ XL,
                                             const u16* __restrict__ XR,
                                             void* __restrict__ out){
  int wave = threadIdx.x >> 6, lane = threadIdx.x & 63;
  int node = blockIdx.x * 4 + wave;
  if (node >= N_NODES) return;
  int start = off[node], cnt = deg[node];
  float inv = invdeg[node];

  if (FW == 128){
    float s0 = 0.f, s1 = 0.f;
    for (int e = 0; e < cnt; ++e){
      int src = cols[start + e];
      unsigned u = ((const unsigned*)XR)[(size_t)src * 64 + lane];   // 2 bf16
      s0 += bf2f((u16)(u & 0xffffu));
      s1 += bf2f((u16)(u >> 16));
    }
    float o0 = XL[(size_t)node * 128 + lane * 2]     + inv * s0;
    float o1 = XL[(size_t)node * 128 + lane * 2 + 1] + inv * s1;
    if (RELU){ o0 = fmaxf(o0, 0.f); o1 = fmaxf(o1, 0.f); }
    if (BF16OUT){
      ((unsigned*)out)[(size_t)node * 64 + lane] =
          (unsigned)f2bf(o0) | ((unsigned)f2bf(o1) << 16);
    } else {
      ((float*)out)[(size_t)node * 128 + lane * 2]     = o0;
      ((float*)out)[(size_t)node * 128 + lane * 2 + 1] = o1;
    }
  } else { // FW == 64
    float s0 = 0.f;
    for (int e = 0; e < cnt; ++e){
      int src = cols[start + e];
      s0 += bf2f(XR[(size_t)src * 64 + lane]);
    }
    float o0 = XL[(size_t)node * 64 + lane] + inv * s0;
    if (RELU) o0 = fmaxf(o0, 0.f);
    if (BF16OUT) ((u16*)out)[(size_t)node * 64 + lane] = f2bf(o0);
    else         ((float*)out)[(size_t)node * 64 + lane] = o0;
  }
}

// ---------------- launch ----------------

extern "C" void kernel_launch(void* const* d_in, const int* in_sizes, int n_in,
                              void* d_out, int out_size, void* d_ws, size_t ws_size,
                              hipStream_t stream) {
  const float* x     = (const float*)d_in[0];
  const int*   edges = (const int*)  d_in[1];
  const float* Wl1 = (const float*)d_in[2];
  const float* Wr1 = (const float*)d_in[3];
  const float* b1  = (const float*)d_in[4];
  const float* Wl2 = (const float*)d_in[5];
  const float* Wr2 = (const float*)d_in[6];
  const float* b2  = (const float*)d_in[7];
  const float* Wl3 = (const float*)d_in[8];
  const float* Wr3 = (const float*)d_in[9];
  const float* b3  = (const float*)d_in[10];

  char* ws = (char*)d_ws;
  size_t o = 0;
  auto alloc = [&](size_t bytes) -> void* {
    void* p = ws + o;
    o += (bytes + 255) & ~(size_t)255;
    return p;
  };
  int*   deg    = (int*)  alloc(N_NODES * 4);
  int*   off    = (int*)  alloc(N_NODES * 4);
  int*   cursor = (int*)  alloc(N_NODES * 4);
  float* invdeg = (float*)alloc(N_NODES * 4);
  int*   bsum   = (int*)  alloc(256 * 4);
  int*   bofs   = (int*)  alloc(256 * 4);
  int*   cols   = (int*)  alloc(N_EDGES * 4);
  u16*   Xb     = (u16*)  alloc((size_t)N_NODES * 128 * 2);
  u16*   XRb    = (u16*)  alloc((size_t)N_NODES * 128 * 2);
  float* XL     = (float*)alloc((size_t)N_NODES * 128 * 4);
  u16*   WT     = (u16*)  alloc(256 * 128 * 2);

  const int NB = (N_NODES + 255) / 256;       // 196
  const int EB = (N_EDGES + 255) / 256;       // 3125

  // CSR build
  k_zero<<<NB, 256, 0, stream>>>(deg, N_NODES);
  k_count<<<EB, 256, 0, stream>>>(edges, deg);
  k_scan_blocks<<<NB, 256, 0, stream>>>(deg, off, bsum);
  k_scan_tops<<<1, 256, 0, stream>>>(bsum, bofs, NB);
  k_scan_add<<<NB, 256, 0, stream>>>(off, bofs, deg, cursor, invdeg);
  k_scatter<<<EB, 256, 0, stream>>>(edges, cursor, cols);

  // x -> bf16
  k_cast<<<(N_NODES * 128 / 4 + 255) / 256, 256, 0, stream>>>(x, Xb);

  const int MG = (N_NODES + 63) / 64;         // 782

  // layer 1: 128 -> 128, relu
  k_wprep<<<(256 * 128 + 255) / 256, 256, 0, stream>>>(Wl1, Wr1, WT, 128);
  { dim3 g(MG, 4); k_gemm<<<g, 256, 0, stream>>>(Xb, WT, b1, XL, XRb, 128); }
  k_agg<128, true, true><<<(N_NODES + 3) / 4, 256, 0, stream>>>(off, deg, invdeg, cols, XL, XRb, Xb);

  // layer 2: 128 -> 128, relu
  k_wprep<<<(256 * 128 + 255) / 256, 256, 0, stream>>>(Wl2, Wr2, WT, 128);
  { dim3 g(MG, 4); k_gemm<<<g, 256, 0, stream>>>(Xb, WT, b2, XL, XRb, 128); }
  k_agg<128, true, true><<<(N_NODES + 3) / 4, 256, 0, stream>>>(off, deg, invdeg, cols, XL, XRb, Xb);

  // layer 3: 128 -> 64, no relu, fp32 out
  k_wprep<<<(128 * 128 + 255) / 256, 256, 0, stream>>>(Wl3, Wr3, WT, 64);
  { dim3 g(MG, 2); k_gemm<<<g, 256, 0, stream>>>(Xb, WT, b3, XL, XRb, 64); }
  k_agg<64, false, false><<<(N_NODES + 3) / 4, 256, 0, stream>>>(off, deg, invdeg, cols, XL, XRb, (float*)d_out);
}

// Round 2
// 334.308 us; speedup vs baseline: 1.4513x; 1.4513x over previous
//
#include <hip/hip_runtime.h>
#include <hip/hip_bf16.h>

#define N_NODES 50000
#define N_EDGES 800000

typedef unsigned short u16;
typedef short v8s __attribute__((ext_vector_type(8)));
typedef float v4f __attribute__((ext_vector_type(4)));

__device__ __forceinline__ u16 f2bf(float f){
  union { float f; unsigned u; } x; x.f = f;
  unsigned u = x.u;
  return (u16)((u + 0x7FFFu + ((u >> 16) & 1u)) >> 16);   // RNE
}
__device__ __forceinline__ float bf2f(u16 s){
  union { unsigned u; float f; } x; x.u = ((unsigned)s) << 16; return x.f;
}

// ---------------- CSR build ----------------

__global__ void k_zero(int* __restrict__ p, int n){
  int i = blockIdx.x * 256 + threadIdx.x;
  if (i < n) p[i] = 0;
}

__global__ void k_count(const int* __restrict__ edges, int* __restrict__ deg){
  int j = blockIdx.x * 256 + threadIdx.x;
  if (j < N_EDGES) atomicAdd(&deg[edges[N_EDGES + j]], 1);
}

__global__ void k_scan_blocks(const int* __restrict__ deg, int* __restrict__ off,
                              int* __restrict__ bsum){
  __shared__ int s[256];
  int tid = threadIdx.x;
  int i = blockIdx.x * 256 + tid;
  int v = (i < N_NODES) ? deg[i] : 0;
  s[tid] = v; __syncthreads();
  for (int d = 1; d < 256; d <<= 1){
    int t = (tid >= d) ? s[tid - d] : 0;
    __syncthreads();
    s[tid] += t;
    __syncthreads();
  }
  if (i < N_NODES) off[i] = s[tid] - v;          // block-local exclusive
  if (tid == 255) bsum[blockIdx.x] = s[tid];     // block total
}

__global__ void k_scan_tops(const int* __restrict__ bsum, int* __restrict__ bofs, int nb){
  __shared__ int s[256];
  int tid = threadIdx.x;
  int v = (tid < nb) ? bsum[tid] : 0;
  s[tid] = v; __syncthreads();
  for (int d = 1; d < 256; d <<= 1){
    int t = (tid >= d) ? s[tid - d] : 0;
    __syncthreads();
    s[tid] += t;
    __syncthreads();
  }
  if (tid < nb) bofs[tid] = s[tid] - v;          // exclusive over blocks
}

__global__ void k_scan_add(int* __restrict__ off, const int* __restrict__ bofs,
                           const int* __restrict__ deg, int* __restrict__ cursor,
                           float* __restrict__ invdeg){
  int i = blockIdx.x * 256 + threadIdx.x;
  if (i < N_NODES){
    int o = off[i] + bofs[blockIdx.x];
    off[i] = o;
    cursor[i] = o;
    int d = deg[i];
    invdeg[i] = 1.0f / (float)(d > 1 ? d : 1);
  }
}

__global__ void k_scatter(const int* __restrict__ edges, int* __restrict__ cursor,
                          int* __restrict__ cols){
  int j = blockIdx.x * 256 + threadIdx.x;
  if (j < N_EDGES){
    int dst = edges[N_EDGES + j];
    int pos = atomicAdd(&cursor[dst], 1);
    cols[pos] = edges[j];
  }
}

// ---------------- fp32 -> bf16 cast of x ----------------

__global__ void k_cast(const float* __restrict__ x, u16* __restrict__ Xb){
  int i = blockIdx.x * 256 + threadIdx.x;      // one per 4 floats
  if (i * 4 < N_NODES * 128){
    float4 v = ((const float4*)x)[i];
    ((ushort4*)Xb)[i] = make_ushort4(f2bf(v.x), f2bf(v.y), f2bf(v.z), f2bf(v.w));
  }
}

// ---------------- weight prep: WT[n][k] = [Wl|Wr]^T, bf16 ----------------

__global__ void k_wprep(const float* __restrict__ Wl, const float* __restrict__ Wr,
                        u16* __restrict__ WT, int N1){
  int idx = blockIdx.x * 256 + threadIdx.x;    // over (2*N1)*128
  int N = 2 * N1;
  if (idx < N * 128){
    int n = idx >> 7, k = idx & 127;
    float v = (n < N1) ? Wl[k * N1 + n] : Wr[k * N1 + (n - N1)];
    WT[n * 128 + k] = f2bf(v);
  }
}

// ---------------- fused GEMM: XL = A@Wl + b (fp32), XR = A@Wr (bf16) ----------------
// A: [M x 128] bf16 row-major.  WT: [2*N1 x 128] bf16 row-major (B^T form).
// grid.x over M/64, grid.y over (2*N1)/64.

__global__ __launch_bounds__(256) void k_gemm(const u16* __restrict__ A,
                                              const u16* __restrict__ WT,
                                              const float* __restrict__ bias,
                                              float* __restrict__ XL,
                                              u16* __restrict__ XR, int N1){
  __shared__ u16 As[64 * 136];   // +8 pad per row, 16B-aligned rows (272 B)
  __shared__ u16 Bs[64 * 136];
  const int tid = threadIdx.x;
  const int rowBase = blockIdx.x * 64;
  const int colBase = blockIdx.y * 64;

  // stage A tile (64x128) and WT tile (64x128) as 16B chunks
  #pragma unroll
  for (int it = 0; it < 4; ++it){
    int chunk = tid + it * 256;          // 0..1023
    int r = chunk >> 4, cseg = chunk & 15;
    int gr = rowBase + r;
    uint4 va = make_uint4(0u, 0u, 0u, 0u);
    if (gr < N_NODES) va = ((const uint4*)(A + (size_t)gr * 128))[cseg];
    ((uint4*)As)[r * 17 + cseg] = va;
    uint4 vb = ((const uint4*)(WT + (size_t)(colBase + r) * 128))[cseg];
    ((uint4*)Bs)[r * 17 + cseg] = vb;
  }
  __syncthreads();

  const int lane = tid & 63, wave = tid >> 6;
  const int quad = lane >> 4, l15 = lane & 15;
  const int wm = wave & 1, wn = wave >> 1;

  v4f acc[2][2] = {};
  #pragma unroll
  for (int kt = 0; kt < 4; ++kt){
    int ko = kt * 32 + quad * 8;
    v8s a0 = *(const v8s*)&As[(wm * 32 + l15) * 136 + ko];
    v8s a1 = *(const v8s*)&As[(wm * 32 + 16 + l15) * 136 + ko];
    v8s b0 = *(const v8s*)&Bs[(wn * 32 + l15) * 136 + ko];
    v8s b1 = *(const v8s*)&Bs[(wn * 32 + 16 + l15) * 136 + ko];
    acc[0][0] = __builtin_amdgcn_mfma_f32_16x16x32_bf16(a0, b0, acc[0][0], 0, 0, 0);
    acc[0][1] = __builtin_amdgcn_mfma_f32_16x16x32_bf16(a0, b1, acc[0][1], 0, 0, 0);
    acc[1][0] = __builtin_amdgcn_mfma_f32_16x16x32_bf16(a1, b0, acc[1][0], 0, 0, 0);
    acc[1][1] = __builtin_amdgcn_mfma_f32_16x16x32_bf16(a1, b1, acc[1][1], 0, 0, 0);
  }

  // epilogue: C/D layout col = lane&15, row = quad*4 + reg
  #pragma unroll
  for (int mi = 0; mi < 2; ++mi)
    #pragma unroll
    for (int ni = 0; ni < 2; ++ni)
      #pragma unroll
      for (int r = 0; r < 4; ++r){
        int grow = rowBase + wm * 32 + mi * 16 + quad * 4 + r;
        int gcol = colBase + wn * 32 + ni * 16 + l15;
        if (grow < N_NODES){
          float v = acc[mi][ni][r];
          if (gcol < N1) XL[(size_t)grow * N1 + gcol] = v + bias[gcol];
          else           XR[(size_t)grow * N1 + (gcol - N1)] = f2bf(v);
        }
      }
}

// ---------------- aggregate + combine (+ReLU, +cast) ----------------
// one wave per node; FW = feature width of this layer's outputs (128 or 64)
// Edge loop runs in predicated chunks of 8: 8 independent col loads, then 8
// independent row gathers -> 2 memory latencies per 8 edges instead of per edge.

template<int FW, bool RELU, bool BF16OUT>
__global__ __launch_bounds__(256) void k_agg(const int* __restrict__ off,
                                             const int* __restrict__ deg,
                                             const float* __restrict__ invdeg,
                                             const int* __restrict__ cols,
                                             const float* __restrict__ XL,
                                             const u16* __restrict__ XR,
                                             void* __restrict__ out){
  int wave = threadIdx.x >> 6, lane = threadIdx.x & 63;
  int node = blockIdx.x * 4 + wave;
  if (node >= N_NODES) return;
  int start = off[node], cnt = deg[node];
  float inv = invdeg[node];

  if (FW == 128){
    float sa[8], sb[8];
    #pragma unroll
    for (int k = 0; k < 8; ++k){ sa[k] = 0.f; sb[k] = 0.f; }
    for (int e = 0; e < cnt; e += 8){
      int srcs[8];
      #pragma unroll
      for (int k = 0; k < 8; ++k){
        int idx = e + k; idx = idx < cnt ? idx : cnt - 1;   // clamp tail
        srcs[k] = cols[start + idx];
      }
      #pragma unroll
      for (int k = 0; k < 8; ++k){
        unsigned u = ((const unsigned*)XR)[(size_t)srcs[k] * 64 + lane];
        if (e + k >= cnt) u = 0u;                           // zero tail (exact)
        sa[k] += bf2f((u16)(u & 0xffffu));
        sb[k] += bf2f((u16)(u >> 16));
      }
    }
    float s0 = ((sa[0] + sa[1]) + (sa[2] + sa[3])) + ((sa[4] + sa[5]) + (sa[6] + sa[7]));
    float s1 = ((sb[0] + sb[1]) + (sb[2] + sb[3])) + ((sb[4] + sb[5]) + (sb[6] + sb[7]));
    float2 xl = ((const float2*)XL)[(size_t)node * 64 + lane];
    float o0 = xl.x + inv * s0;
    float o1 = xl.y + inv * s1;
    if (RELU){ o0 = fmaxf(o0, 0.f); o1 = fmaxf(o1, 0.f); }
    if (BF16OUT){
      ((unsigned*)out)[(size_t)node * 64 + lane] =
          (unsigned)f2bf(o0) | ((unsigned)f2bf(o1) << 16);
    } else {
      ((float2*)out)[(size_t)node * 64 + lane] = make_float2(o0, o1);
    }
  } else { // FW == 64
    float sa[8];
    #pragma unroll
    for (int k = 0; k < 8; ++k) sa[k] = 0.f;
    for (int e = 0; e < cnt; e += 8){
      int srcs[8];
      #pragma unroll
      for (int k = 0; k < 8; ++k){
        int idx = e + k; idx = idx < cnt ? idx : cnt - 1;
        srcs[k] = cols[start + idx];
      }
      #pragma unroll
      for (int k = 0; k < 8; ++k){
        float v = bf2f(XR[(size_t)srcs[k] * 64 + lane]);
        if (e + k >= cnt) v = 0.f;
        sa[k] += v;
      }
    }
    float s0 = ((sa[0] + sa[1]) + (sa[2] + sa[3])) + ((sa[4] + sa[5]) + (sa[6] + sa[7]));
    float o0 = XL[(size_t)node * 64 + lane] + inv * s0;
    if (RELU) o0 = fmaxf(o0, 0.f);
    if (BF16OUT) ((u16*)out)[(size_t)node * 64 + lane] = f2bf(o0);
    else         ((float*)out)[(size_t)node * 64 + lane] = o0;
  }
}

// ---------------- launch ----------------

extern "C" void kernel_launch(void* const* d_in, const int* in_sizes, int n_in,
                              void* d_out, int out_size, void* d_ws, size_t ws_size,
                              hipStream_t stream) {
  const float* x     = (const float*)d_in[0];
  const int*   edges = (const int*)  d_in[1];
  const float* Wl1 = (const float*)d_in[2];
  const float* Wr1 = (const float*)d_in[3];
  const float* b1  = (const float*)d_in[4];
  const float* Wl2 = (const float*)d_in[5];
  const float* Wr2 = (const float*)d_in[6];
  const float* b2  = (const float*)d_in[7];
  const float* Wl3 = (const float*)d_in[8];
  const float* Wr3 = (const float*)d_in[9];
  const float* b3  = (const float*)d_in[10];

  char* ws = (char*)d_ws;
  size_t o = 0;
  auto alloc = [&](size_t bytes) -> void* {
    void* p = ws + o;
    o += (bytes + 255) & ~(size_t)255;
    return p;
  };
  int*   deg    = (int*)  alloc(N_NODES * 4);
  int*   off    = (int*)  alloc(N_NODES * 4);
  int*   cursor = (int*)  alloc(N_NODES * 4);
  float* invdeg = (float*)alloc(N_NODES * 4);
  int*   bsum   = (int*)  alloc(256 * 4);
  int*   bofs   = (int*)  alloc(256 * 4);
  int*   cols   = (int*)  alloc(N_EDGES * 4);
  u16*   Xb     = (u16*)  alloc((size_t)N_NODES * 128 * 2);
  u16*   XRb    = (u16*)  alloc((size_t)N_NODES * 128 * 2);
  float* XL     = (float*)alloc((size_t)N_NODES * 128 * 4);
  u16*   WT     = (u16*)  alloc(256 * 128 * 2);

  const int NB = (N_NODES + 255) / 256;       // 196
  const int EB = (N_EDGES + 255) / 256;       // 3125

  // CSR build
  k_zero<<<NB, 256, 0, stream>>>(deg, N_NODES);
  k_count<<<EB, 256, 0, stream>>>(edges, deg);
  k_scan_blocks<<<NB, 256, 0, stream>>>(deg, off, bsum);
  k_scan_tops<<<1, 256, 0, stream>>>(bsum, bofs, NB);
  k_scan_add<<<NB, 256, 0, stream>>>(off, bofs, deg, cursor, invdeg);
  k_scatter<<<EB, 256, 0, stream>>>(edges, cursor, cols);

  // x -> bf16
  k_cast<<<(N_NODES * 128 / 4 + 255) / 256, 256, 0, stream>>>(x, Xb);

  const int MG = (N_NODES + 63) / 64;         // 782

  // layer 1: 128 -> 128, relu
  k_wprep<<<(256 * 128 + 255) / 256, 256, 0, stream>>>(Wl1, Wr1, WT, 128);
  { dim3 g(MG, 4); k_gemm<<<g, 256, 0, stream>>>(Xb, WT, b1, XL, XRb, 128); }
  k_agg<128, true, true><<<(N_NODES + 3) / 4, 256, 0, stream>>>(off, deg, invdeg, cols, XL, XRb, Xb);

  // layer 2: 128 -> 128, relu
  k_wprep<<<(256 * 128 + 255) / 256, 256, 0, stream>>>(Wl2, Wr2, WT, 128);
  { dim3 g(MG, 4); k_gemm<<<g, 256, 0, stream>>>(Xb, WT, b2, XL, XRb, 128); }
  k_agg<128, true, true><<<(N_NODES + 3) / 4, 256, 0, stream>>>(off, deg, invdeg, cols, XL, XRb, Xb);

  // layer 3: 128 -> 64, no relu, fp32 out
  k_wprep<<<(128 * 128 + 255) / 256, 256, 0, stream>>>(Wl3, Wr3, WT, 64);
  { dim3 g(MG, 2); k_gemm<<<g, 256, 0, stream>>>(Xb, WT, b3, XL, XRb, 64); }
  k_agg<64, false, false><<<(N_NODES + 3) / 4, 256, 0, stream>>>(off, deg, invdeg, cols, XL, XRb, (float*)d_out);
}

// Round 3
// 299.380 us; speedup vs baseline: 1.6206x; 1.1167x over previous
//
#include <hip/hip_runtime.h>
#include <hip/hip_bf16.h>

#define N_NODES 50000
#define N_EDGES 800000
#define NBKT 196           // ceil(50000/256) buckets of 256 nodes
#define ACHUNK 4096        // edges per block in binning kernels

typedef unsigned short u16;
typedef short v8s __attribute__((ext_vector_type(8)));
typedef float v4f __attribute__((ext_vector_type(4)));

__device__ __forceinline__ u16 f2bf(float f){
  union { float f; unsigned u; } x; x.f = f;
  unsigned u = x.u;
  return (u16)((u + 0x7FFFu + ((u >> 16) & 1u)) >> 16);   // RNE
}
__device__ __forceinline__ float bf2f(u16 s){
  union { unsigned u; float f; } x; x.u = ((unsigned)s) << 16; return x.f;
}

// ---------------- CSR build: block-aggregated two-level binning ----------------

__global__ void k_zero(int* __restrict__ p, int n){
  int i = blockIdx.x * 256 + threadIdx.x;
  if (i < n) p[i] = 0;
}

// A1: bucket counts via per-block LDS histogram (196 global atomics per block)
__global__ __launch_bounds__(256) void kA1(const int* __restrict__ edges,
                                           int* __restrict__ bcnt){
  __shared__ int h[NBKT];
  int tid = threadIdx.x;
  for (int i = tid; i < NBKT; i += 256) h[i] = 0;
  __syncthreads();
  int base = blockIdx.x * ACHUNK;
  for (int i = tid; i < ACHUNK; i += 256){
    int j = base + i;
    if (j < N_EDGES) atomicAdd(&h[edges[N_EDGES + j] >> 8], 1);
  }
  __syncthreads();
  for (int i = tid; i < NBKT; i += 256)
    if (h[i]) atomicAdd(&bcnt[i], h[i]);
}

// scan bucket counts -> bbase (exclusive, +total at end), init bcur
__global__ __launch_bounds__(256) void k_scanb(const int* __restrict__ bcnt,
                                               int* __restrict__ bbase,
                                               int* __restrict__ bcur){
  __shared__ int s[256];
  int tid = threadIdx.x;
  int v = (tid < NBKT) ? bcnt[tid] : 0;
  s[tid] = v; __syncthreads();
  for (int d = 1; d < 256; d <<= 1){
    int t = (tid >= d) ? s[tid - d] : 0;
    __syncthreads();
    s[tid] += t;
    __syncthreads();
  }
  if (tid < NBKT){ bbase[tid] = s[tid] - v; bcur[tid] = s[tid] - v; }
  if (tid == NBKT - 1) bbase[NBKT] = s[tid];
}

// A2: scatter (src,dst) pairs into bucket-major order; per-block contiguous spans
__global__ __launch_bounds__(256) void kA2(const int* __restrict__ edges,
                                           int* __restrict__ bcur,
                                           int2* __restrict__ pairs){
  __shared__ int h[NBKT];
  int tid = threadIdx.x;
  for (int i = tid; i < NBKT; i += 256) h[i] = 0;
  __syncthreads();
  int base = blockIdx.x * ACHUNK;
  for (int i = tid; i < ACHUNK; i += 256){
    int j = base + i;
    if (j < N_EDGES) atomicAdd(&h[edges[N_EDGES + j] >> 8], 1);
  }
  __syncthreads();
  // reserve a contiguous span per bucket for this block
  for (int i = tid; i < NBKT; i += 256)
    h[i] = h[i] ? atomicAdd(&bcur[i], h[i]) : 0;   // h becomes block-local cursor
  __syncthreads();
  for (int i = tid; i < ACHUNK; i += 256){
    int j = base + i;
    if (j < N_EDGES){
      int s = edges[j], d = edges[N_EDGES + j];
      int pos = atomicAdd(&h[d >> 8], 1);
      pairs[pos] = make_int2(s, d);
    }
  }
}

// B: one block per bucket — LDS counting sort; writes off/deg/invdeg + cols densely
__global__ __launch_bounds__(256) void kB(const int2* __restrict__ pairs,
                                          const int* __restrict__ bbase,
                                          int* __restrict__ off,
                                          int* __restrict__ deg,
                                          float* __restrict__ invdeg,
                                          int* __restrict__ cols){
  __shared__ int h[256];
  __shared__ int s[256];
  __shared__ int cur[256];
  int tid = threadIdx.x;
  int bkt = blockIdx.x;
  int base = bbase[bkt], cnt = bbase[bkt + 1] - base;
  int nodeBase = bkt << 8;

  h[tid] = 0; __syncthreads();
  for (int i = tid; i < cnt; i += 256){
    int2 p = pairs[base + i];
    atomicAdd(&h[p.y - nodeBase], 1);
  }
  __syncthreads();
  int v = h[tid];
  s[tid] = v; __syncthreads();
  for (int d = 1; d < 256; d <<= 1){
    int t = (tid >= d) ? s[tid - d] : 0;
    __syncthreads();
    s[tid] += t;
    __syncthreads();
  }
  int excl = s[tid] - v;
  int node = nodeBase + tid;
  if (node < N_NODES){
    off[node] = base + excl;
    deg[node] = v;
    invdeg[node] = 1.0f / (float)(v > 1 ? v : 1);
  }
  cur[tid] = base + excl;
  __syncthreads();
  for (int i = tid; i < cnt; i += 256){
    int2 p = pairs[base + i];
    int pos = atomicAdd(&cur[p.y - nodeBase], 1);
    cols[pos] = p.x;
  }
}

// ---------------- fp32 -> bf16 cast of x ----------------

__global__ void k_cast(const float* __restrict__ x, u16* __restrict__ Xb){
  int i = blockIdx.x * 256 + threadIdx.x;      // one per 4 floats
  if (i * 4 < N_NODES * 128){
    float4 v = ((const float4*)x)[i];
    ((ushort4*)Xb)[i] = make_ushort4(f2bf(v.x), f2bf(v.y), f2bf(v.z), f2bf(v.w));
  }
}

// ---------------- weight prep: WT[n][k] = [Wl|Wr]^T, bf16 ----------------

__global__ void k_wprep(const float* __restrict__ Wl, const float* __restrict__ Wr,
                        u16* __restrict__ WT, int N1){
  int idx = blockIdx.x * 256 + threadIdx.x;    // over (2*N1)*128
  int N = 2 * N1;
  if (idx < N * 128){
    int n = idx >> 7, k = idx & 127;
    float v = (n < N1) ? Wl[k * N1 + n] : Wr[k * N1 + (n - N1)];
    WT[n * 128 + k] = f2bf(v);
  }
}

// ---------------- fused GEMM: XL = A@Wl + b (fp32), XR = A@Wr (bf16) ----------------

__global__ __launch_bounds__(256) void k_gemm(const u16* __restrict__ A,
                                              const u16* __restrict__ WT,
                                              const float* __restrict__ bias,
                                              float* __restrict__ XL,
                                              u16* __restrict__ XR, int N1){
  __shared__ u16 As[64 * 136];
  __shared__ u16 Bs[64 * 136];
  const int tid = threadIdx.x;
  const int rowBase = blockIdx.x * 64;
  const int colBase = blockIdx.y * 64;

  #pragma unroll
  for (int it = 0; it < 4; ++it){
    int chunk = tid + it * 256;
    int r = chunk >> 4, cseg = chunk & 15;
    int gr = rowBase + r;
    uint4 va = make_uint4(0u, 0u, 0u, 0u);
    if (gr < N_NODES) va = ((const uint4*)(A + (size_t)gr * 128))[cseg];
    ((uint4*)As)[r * 17 + cseg] = va;
    uint4 vb = ((const uint4*)(WT + (size_t)(colBase + r) * 128))[cseg];
    ((uint4*)Bs)[r * 17 + cseg] = vb;
  }
  __syncthreads();

  const int lane = tid & 63, wave = tid >> 6;
  const int quad = lane >> 4, l15 = lane & 15;
  const int wm = wave & 1, wn = wave >> 1;

  v4f acc[2][2] = {};
  #pragma unroll
  for (int kt = 0; kt < 4; ++kt){
    int ko = kt * 32 + quad * 8;
    v8s a0 = *(const v8s*)&As[(wm * 32 + l15) * 136 + ko];
    v8s a1 = *(const v8s*)&As[(wm * 32 + 16 + l15) * 136 + ko];
    v8s b0 = *(const v8s*)&Bs[(wn * 32 + l15) * 136 + ko];
    v8s b1 = *(const v8s*)&Bs[(wn * 32 + 16 + l15) * 136 + ko];
    acc[0][0] = __builtin_amdgcn_mfma_f32_16x16x32_bf16(a0, b0, acc[0][0], 0, 0, 0);
    acc[0][1] = __builtin_amdgcn_mfma_f32_16x16x32_bf16(a0, b1, acc[0][1], 0, 0, 0);
    acc[1][0] = __builtin_amdgcn_mfma_f32_16x16x32_bf16(a1, b0, acc[1][0], 0, 0, 0);
    acc[1][1] = __builtin_amdgcn_mfma_f32_16x16x32_bf16(a1, b1, acc[1][1], 0, 0, 0);
  }

  #pragma unroll
  for (int mi = 0; mi < 2; ++mi)
    #pragma unroll
    for (int ni = 0; ni < 2; ++ni)
      #pragma unroll
      for (int r = 0; r < 4; ++r){
        int grow = rowBase + wm * 32 + mi * 16 + quad * 4 + r;
        int gcol = colBase + wn * 32 + ni * 16 + l15;
        if (grow < N_NODES){
          float v = acc[mi][ni][r];
          if (gcol < N1) XL[(size_t)grow * N1 + gcol] = v + bias[gcol];
          else           XR[(size_t)grow * N1 + (gcol - N1)] = f2bf(v);
        }
      }
}

// ---------------- aggregate + combine (+ReLU, +cast) ----------------
// half-wave (32 lanes) per edge, 8B loads: 16 edges in flight per wave.

template<bool RELU>
__global__ __launch_bounds__(256) void k_agg128(const int* __restrict__ off,
                                                const int* __restrict__ deg,
                                                const float* __restrict__ invdeg,
                                                const int* __restrict__ cols,
                                                const float* __restrict__ XL,
                                                const u16* __restrict__ XR,
                                                unsigned* __restrict__ out){
  int wave = threadIdx.x >> 6, lane = threadIdx.x & 63;
  int node = blockIdx.x * 4 + wave;
  if (node >= N_NODES) return;
  int start = off[node], cnt = deg[node];
  float inv = invdeg[node];
  int h = lane >> 5, l32 = lane & 31;
  const uint2* XR2 = (const uint2*)XR;   // row = 32 uint2 (128 bf16)

  float acc[8][4] = {};
  for (int e = 0; e < cnt; e += 16){
    int srcs[8];
    #pragma unroll
    for (int k = 0; k < 8; ++k){
      int id = e + 2 * k + h; id = id < cnt ? id : cnt - 1;
      srcs[k] = cols[start + id];
    }
    #pragma unroll
    for (int k = 0; k < 8; ++k){
      uint2 u = XR2[(size_t)srcs[k] * 32 + l32];
      if (e + 2 * k + h >= cnt){ u.x = 0u; u.y = 0u; }
      acc[k][0] += bf2f((u16)(u.x & 0xffffu));
      acc[k][1] += bf2f((u16)(u.x >> 16));
      acc[k][2] += bf2f((u16)(u.y & 0xffffu));
      acc[k][3] += bf2f((u16)(u.y >> 16));
    }
  }
  float s0[4];
  #pragma unroll
  for (int f = 0; f < 4; ++f){
    s0[f] = ((acc[0][f] + acc[1][f]) + (acc[2][f] + acc[3][f]))
          + ((acc[4][f] + acc[5][f]) + (acc[6][f] + acc[7][f]));
    s0[f] += __shfl_down(s0[f], 32);
  }
  if (h == 0){
    float4 xl = ((const float4*)XL)[(size_t)node * 32 + l32];
    float o0 = xl.x + inv * s0[0];
    float o1 = xl.y + inv * s0[1];
    float o2 = xl.z + inv * s0[2];
    float o3 = xl.w + inv * s0[3];
    if (RELU){
      o0 = fmaxf(o0, 0.f); o1 = fmaxf(o1, 0.f);
      o2 = fmaxf(o2, 0.f); o3 = fmaxf(o3, 0.f);
    }
    uint2 ov;
    ov.x = (unsigned)f2bf(o0) | ((unsigned)f2bf(o1) << 16);
    ov.y = (unsigned)f2bf(o2) | ((unsigned)f2bf(o3) << 16);
    ((uint2*)out)[(size_t)node * 32 + l32] = ov;
  }
}

__global__ __launch_bounds__(256) void k_agg64(const int* __restrict__ off,
                                               const int* __restrict__ deg,
                                               const float* __restrict__ invdeg,
                                               const int* __restrict__ cols,
                                               const float* __restrict__ XL,
                                               const u16* __restrict__ XR,
                                               float* __restrict__ out){
  int wave = threadIdx.x >> 6, lane = threadIdx.x & 63;
  int node = blockIdx.x * 4 + wave;
  if (node >= N_NODES) return;
  int start = off[node], cnt = deg[node];
  float inv = invdeg[node];
  int h = lane >> 5, l32 = lane & 31;
  const unsigned* XRu = (const unsigned*)XR;  // row = 32 uint (64 bf16)

  float acc[8][2] = {};
  for (int e = 0; e < cnt; e += 16){
    int srcs[8];
    #pragma unroll
    for (int k = 0; k < 8; ++k){
      int id = e + 2 * k + h; id = id < cnt ? id : cnt - 1;
      srcs[k] = cols[start + id];
    }
    #pragma unroll
    for (int k = 0; k < 8; ++k){
      unsigned u = XRu[(size_t)srcs[k] * 32 + l32];
      if (e + 2 * k + h >= cnt) u = 0u;
      acc[k][0] += bf2f((u16)(u & 0xffffu));
      acc[k][1] += bf2f((u16)(u >> 16));
    }
  }
  float s0[2];
  #pragma unroll
  for (int f = 0; f < 2; ++f){
    s0[f] = ((acc[0][f] + acc[1][f]) + (acc[2][f] + acc[3][f]))
          + ((acc[4][f] + acc[5][f]) + (acc[6][f] + acc[7][f]));
    s0[f] += __shfl_down(s0[f], 32);
  }
  if (h == 0){
    float2 xl = ((const float2*)XL)[(size_t)node * 32 + l32];
    float o0 = xl.x + inv * s0[0];
    float o1 = xl.y + inv * s0[1];
    ((float2*)out)[(size_t)node * 32 + l32] = make_float2(o0, o1);
  }
}

// ---------------- launch ----------------

extern "C" void kernel_launch(void* const* d_in, const int* in_sizes, int n_in,
                              void* d_out, int out_size, void* d_ws, size_t ws_size,
                              hipStream_t stream) {
  const float* x     = (const float*)d_in[0];
  const int*   edges = (const int*)  d_in[1];
  const float* Wl1 = (const float*)d_in[2];
  const float* Wr1 = (const float*)d_in[3];
  const float* b1  = (const float*)d_in[4];
  const float* Wl2 = (const float*)d_in[5];
  const float* Wr2 = (const float*)d_in[6];
  const float* b2  = (const float*)d_in[7];
  const float* Wl3 = (const float*)d_in[8];
  const float* Wr3 = (const float*)d_in[9];
  const float* b3  = (const float*)d_in[10];

  char* ws = (char*)d_ws;
  size_t o = 0;
  auto alloc = [&](size_t bytes) -> void* {
    void* p = ws + o;
    o += (bytes + 255) & ~(size_t)255;
    return p;
  };
  int*   deg    = (int*)  alloc(N_NODES * 4);
  int*   off    = (int*)  alloc(N_NODES * 4);
  float* invdeg = (float*)alloc(N_NODES * 4);
  int*   bcnt   = (int*)  alloc(NBKT * 4);
  int*   bbase  = (int*)  alloc((NBKT + 1) * 4);
  int*   bcur   = (int*)  alloc(NBKT * 4);
  int2*  pairs  = (int2*) alloc((size_t)N_EDGES * 8);
  int*   cols   = (int*)  alloc(N_EDGES * 4);
  u16*   Xb     = (u16*)  alloc((size_t)N_NODES * 128 * 2);
  u16*   XRb    = (u16*)  alloc((size_t)N_NODES * 128 * 2);
  float* XL     = (float*)alloc((size_t)N_NODES * 128 * 4);
  u16*   WT     = (u16*)  alloc(256 * 128 * 2);

  const int AB = (N_EDGES + ACHUNK - 1) / ACHUNK;   // 196

  // CSR build (two-level binning)
  k_zero<<<1, 256, 0, stream>>>(bcnt, NBKT);
  kA1<<<AB, 256, 0, stream>>>(edges, bcnt);
  k_scanb<<<1, 256, 0, stream>>>(bcnt, bbase, bcur);
  kA2<<<AB, 256, 0, stream>>>(edges, bcur, pairs);
  kB<<<NBKT, 256, 0, stream>>>(pairs, bbase, off, deg, invdeg, cols);

  // x -> bf16
  k_cast<<<(N_NODES * 128 / 4 + 255) / 256, 256, 0, stream>>>(x, Xb);

  const int MG = (N_NODES + 63) / 64;         // 782

  // layer 1: 128 -> 128, relu
  k_wprep<<<(256 * 128 + 255) / 256, 256, 0, stream>>>(Wl1, Wr1, WT, 128);
  { dim3 g(MG, 4); k_gemm<<<g, 256, 0, stream>>>(Xb, WT, b1, XL, XRb, 128); }
  k_agg128<true><<<(N_NODES + 3) / 4, 256, 0, stream>>>(off, deg, invdeg, cols, XL, XRb, (unsigned*)Xb);

  // layer 2: 128 -> 128, relu
  k_wprep<<<(256 * 128 + 255) / 256, 256, 0, stream>>>(Wl2, Wr2, WT, 128);
  { dim3 g(MG, 4); k_gemm<<<g, 256, 0, stream>>>(Xb, WT, b2, XL, XRb, 128); }
  k_agg128<true><<<(N_NODES + 3) / 4, 256, 0, stream>>>(off, deg, invdeg, cols, XL, XRb, (unsigned*)Xb);

  // layer 3: 128 -> 64, no relu, fp32 out
  k_wprep<<<(128 * 128 + 255) / 256, 256, 0, stream>>>(Wl3, Wr3, WT, 64);
  { dim3 g(MG, 2); k_gemm<<<g, 256, 0, stream>>>(Xb, WT, b3, XL, XRb, 64); }
  k_agg64<<<(N_NODES + 3) / 4, 256, 0, stream>>>(off, deg, invdeg, cols, XL, XRb, (float*)d_out);
}

// Round 4
// 271.589 us; speedup vs baseline: 1.7864x; 1.1023x over previous
//
#include <hip/hip_runtime.h>
#include <hip/hip_bf16.h>

#define N_NODES 50000
#define N_EDGES 800000
#define NBKT 196           // ceil(50000/256) buckets of 256 nodes
#define ACHUNK 4096        // edges per block in binning kernels
#define CASTB 6250         // 50000*128/4 float4 chunks / 256 threads

typedef unsigned short u16;
typedef short v8s __attribute__((ext_vector_type(8)));
typedef float v4f __attribute__((ext_vector_type(4)));

__device__ __forceinline__ u16 f2bf(float f){
  union { float f; unsigned u; } x; x.f = f;
  unsigned u = x.u;
  return (u16)((u + 0x7FFFu + ((u >> 16) & 1u)) >> 16);   // RNE
}
__device__ __forceinline__ float bf2f(u16 s){
  union { unsigned u; float f; } x; x.u = ((unsigned)s) << 16; return x.f;
}

// ---------------- fused prep: cast x->bf16, 3x weight transpose, zero bcnt ----

__device__ __forceinline__ void wprep1(const float* __restrict__ Wl,
                                       const float* __restrict__ Wr,
                                       u16* __restrict__ WT, int N1, int idx){
  int n = idx >> 7, k = idx & 127;
  float v = (n < N1) ? Wl[k * N1 + n] : Wr[k * N1 + (n - N1)];
  WT[n * 128 + k] = f2bf(v);
}

__global__ __launch_bounds__(256) void k_prep(const float* __restrict__ x,
                                              u16* __restrict__ Xb,
                                              const float* __restrict__ Wl1,
                                              const float* __restrict__ Wr1,
                                              const float* __restrict__ Wl2,
                                              const float* __restrict__ Wr2,
                                              const float* __restrict__ Wl3,
                                              const float* __restrict__ Wr3,
                                              u16* __restrict__ WT1,
                                              u16* __restrict__ WT2,
                                              u16* __restrict__ WT3,
                                              int* __restrict__ bcnt){
  int b = blockIdx.x, tid = threadIdx.x;
  if (b < CASTB){
    int i = b * 256 + tid;                       // exact: 6250*256 = 1.6M float4
    float4 v = ((const float4*)x)[i];
    ((ushort4*)Xb)[i] = make_ushort4(f2bf(v.x), f2bf(v.y), f2bf(v.z), f2bf(v.w));
  } else if (b < CASTB + 128){
    if (b == CASTB && tid < NBKT) bcnt[tid] = 0;
    wprep1(Wl1, Wr1, WT1, 128, (b - CASTB) * 256 + tid);
  } else if (b < CASTB + 256){
    wprep1(Wl2, Wr2, WT2, 128, (b - CASTB - 128) * 256 + tid);
  } else {
    wprep1(Wl3, Wr3, WT3, 64, (b - CASTB - 256) * 256 + tid);   // 64 blocks
  }
}

// ---------------- CSR build: block-aggregated two-level binning ----------------

__global__ __launch_bounds__(256) void kA1(const int* __restrict__ edges,
                                           int* __restrict__ bcnt){
  __shared__ int h[NBKT];
  int tid = threadIdx.x;
  for (int i = tid; i < NBKT; i += 256) h[i] = 0;
  __syncthreads();
  int base = blockIdx.x * ACHUNK;
  for (int i = tid; i < ACHUNK; i += 256){
    int j = base + i;
    if (j < N_EDGES) atomicAdd(&h[edges[N_EDGES + j] >> 8], 1);
  }
  __syncthreads();
  for (int i = tid; i < NBKT; i += 256)
    if (h[i]) atomicAdd(&bcnt[i], h[i]);
}

__global__ __launch_bounds__(256) void k_scanb(const int* __restrict__ bcnt,
                                               int* __restrict__ bbase,
                                               int* __restrict__ bcur){
  __shared__ int s[256];
  int tid = threadIdx.x;
  int v = (tid < NBKT) ? bcnt[tid] : 0;
  s[tid] = v; __syncthreads();
  for (int d = 1; d < 256; d <<= 1){
    int t = (tid >= d) ? s[tid - d] : 0;
    __syncthreads();
    s[tid] += t;
    __syncthreads();
  }
  if (tid < NBKT){ bbase[tid] = s[tid] - v; bcur[tid] = s[tid] - v; }
  if (tid == NBKT - 1) bbase[NBKT] = s[tid];
}

__global__ __launch_bounds__(256) void kA2(const int* __restrict__ edges,
                                           int* __restrict__ bcur,
                                           int2* __restrict__ pairs){
  __shared__ int h[NBKT];
  int tid = threadIdx.x;
  for (int i = tid; i < NBKT; i += 256) h[i] = 0;
  __syncthreads();
  int base = blockIdx.x * ACHUNK;
  for (int i = tid; i < ACHUNK; i += 256){
    int j = base + i;
    if (j < N_EDGES) atomicAdd(&h[edges[N_EDGES + j] >> 8], 1);
  }
  __syncthreads();
  for (int i = tid; i < NBKT; i += 256)
    h[i] = h[i] ? atomicAdd(&bcur[i], h[i]) : 0;   // h becomes block-local cursor
  __syncthreads();
  for (int i = tid; i < ACHUNK; i += 256){
    int j = base + i;
    if (j < N_EDGES){
      int s = edges[j], d = edges[N_EDGES + j];
      int pos = atomicAdd(&h[d >> 8], 1);
      pairs[pos] = make_int2(s, d);
    }
  }
}

__global__ __launch_bounds__(256) void kB(const int2* __restrict__ pairs,
                                          const int* __restrict__ bbase,
                                          int* __restrict__ off,
                                          int* __restrict__ deg,
                                          float* __restrict__ invdeg,
                                          int* __restrict__ cols){
  __shared__ int h[256];
  __shared__ int s[256];
  __shared__ int cur[256];
  int tid = threadIdx.x;
  int bkt = blockIdx.x;
  int base = bbase[bkt], cnt = bbase[bkt + 1] - base;
  int nodeBase = bkt << 8;

  h[tid] = 0; __syncthreads();
  for (int i = tid; i < cnt; i += 256){
    int2 p = pairs[base + i];
    atomicAdd(&h[p.y - nodeBase], 1);
  }
  __syncthreads();
  int v = h[tid];
  s[tid] = v; __syncthreads();
  for (int d = 1; d < 256; d <<= 1){
    int t = (tid >= d) ? s[tid - d] : 0;
    __syncthreads();
    s[tid] += t;
    __syncthreads();
  }
  int excl = s[tid] - v;
  int node = nodeBase + tid;
  if (node < N_NODES){
    off[node] = base + excl;
    deg[node] = v;
    invdeg[node] = 1.0f / (float)(v > 1 ? v : 1);
  }
  cur[tid] = base + excl;
  __syncthreads();
  for (int i = tid; i < cnt; i += 256){
    int2 p = pairs[base + i];
    int pos = atomicAdd(&cur[p.y - nodeBase], 1);
    cols[pos] = p.x;
  }
}

// ---------------- fused GEMM: XL = A@Wl + b (fp32), XR = A@Wr (bf16) ----------------

__global__ __launch_bounds__(256) void k_gemm(const u16* __restrict__ A,
                                              const u16* __restrict__ WT,
                                              const float* __restrict__ bias,
                                              float* __restrict__ XL,
                                              u16* __restrict__ XR, int N1){
  __shared__ u16 As[64 * 136];
  __shared__ u16 Bs[64 * 136];
  const int tid = threadIdx.x;
  const int rowBase = blockIdx.x * 64;
  const int colBase = blockIdx.y * 64;

  #pragma unroll
  for (int it = 0; it < 4; ++it){
    int chunk = tid + it * 256;
    int r = chunk >> 4, cseg = chunk & 15;
    int gr = rowBase + r;
    uint4 va = make_uint4(0u, 0u, 0u, 0u);
    if (gr < N_NODES) va = ((const uint4*)(A + (size_t)gr * 128))[cseg];
    ((uint4*)As)[r * 17 + cseg] = va;
    uint4 vb = ((const uint4*)(WT + (size_t)(colBase + r) * 128))[cseg];
    ((uint4*)Bs)[r * 17 + cseg] = vb;
  }
  __syncthreads();

  const int lane = tid & 63, wave = tid >> 6;
  const int quad = lane >> 4, l15 = lane & 15;
  const int wm = wave & 1, wn = wave >> 1;

  v4f acc[2][2] = {};
  #pragma unroll
  for (int kt = 0; kt < 4; ++kt){
    int ko = kt * 32 + quad * 8;
    v8s a0 = *(const v8s*)&As[(wm * 32 + l15) * 136 + ko];
    v8s a1 = *(const v8s*)&As[(wm * 32 + 16 + l15) * 136 + ko];
    v8s b0 = *(const v8s*)&Bs[(wn * 32 + l15) * 136 + ko];
    v8s b1 = *(const v8s*)&Bs[(wn * 32 + 16 + l15) * 136 + ko];
    acc[0][0] = __builtin_amdgcn_mfma_f32_16x16x32_bf16(a0, b0, acc[0][0], 0, 0, 0);
    acc[0][1] = __builtin_amdgcn_mfma_f32_16x16x32_bf16(a0, b1, acc[0][1], 0, 0, 0);
    acc[1][0] = __builtin_amdgcn_mfma_f32_16x16x32_bf16(a1, b0, acc[1][0], 0, 0, 0);
    acc[1][1] = __builtin_amdgcn_mfma_f32_16x16x32_bf16(a1, b1, acc[1][1], 0, 0, 0);
  }

  #pragma unroll
  for (int mi = 0; mi < 2; ++mi)
    #pragma unroll
    for (int ni = 0; ni < 2; ++ni)
      #pragma unroll
      for (int r = 0; r < 4; ++r){
        int grow = rowBase + wm * 32 + mi * 16 + quad * 4 + r;
        int gcol = colBase + wn * 32 + ni * 16 + l15;
        if (grow < N_NODES){
          float v = acc[mi][ni][r];
          if (gcol < N1) XL[(size_t)grow * N1 + gcol] = v + bias[gcol];
          else           XR[(size_t)grow * N1 + (gcol - N1)] = f2bf(v);
        }
      }
}

// ---------------- aggregate + combine (+ReLU, +cast) ----------------
// quarter-wave (16 lanes) per edge row, uint4 loads: 1 load instr per edge row.

template<bool RELU>
__global__ __launch_bounds__(256) void k_agg128(const int* __restrict__ off,
                                                const int* __restrict__ deg,
                                                const float* __restrict__ invdeg,
                                                const int* __restrict__ cols,
                                                const float* __restrict__ XL,
                                                const u16* __restrict__ XR,
                                                uint4* __restrict__ out){
  int wave = threadIdx.x >> 6, lane = threadIdx.x & 63;
  int node = blockIdx.x * 4 + wave;
  if (node >= N_NODES) return;
  int start = off[node], cnt = deg[node];
  float inv = invdeg[node];
  int q = lane >> 4, f = lane & 15;
  const uint4* __restrict__ XR4 = (const uint4*)XR;   // row = 16 uint4
  const int* __restrict__ cbase = cols + start + q;

  float2 a0 = make_float2(0.f, 0.f), a1 = a0, a2 = a0, a3 = a0;
  auto accum = [&](uint4 u){
    a0.x += bf2f((u16)(u.x & 0xffffu)); a0.y += bf2f((u16)(u.x >> 16));
    a1.x += bf2f((u16)(u.y & 0xffffu)); a1.y += bf2f((u16)(u.y >> 16));
    a2.x += bf2f((u16)(u.z & 0xffffu)); a2.y += bf2f((u16)(u.z >> 16));
    a3.x += bf2f((u16)(u.w & 0xffffu)); a3.y += bf2f((u16)(u.w >> 16));
  };

  int nfull = cnt & ~15;
  int e = 0;
  for (; e < nfull; e += 16){
    int s0 = cbase[e], s1 = cbase[e + 4], s2 = cbase[e + 8], s3 = cbase[e + 12];
    uint4 u0 = XR4[(size_t)s0 * 16 + f];
    uint4 u1 = XR4[(size_t)s1 * 16 + f];
    uint4 u2 = XR4[(size_t)s2 * 16 + f];
    uint4 u3 = XR4[(size_t)s3 * 16 + f];
    accum(u0); accum(u1); accum(u2); accum(u3);
  }
  if (e < cnt){                                   // masked tail, exact
    int last = cnt - 1;
    int i0 = e + q, i1 = e + 4 + q, i2 = e + 8 + q, i3 = e + 12 + q;
    int s0 = cols[start + (i0 < last ? i0 : last)];
    int s1 = cols[start + (i1 < last ? i1 : last)];
    int s2 = cols[start + (i2 < last ? i2 : last)];
    int s3 = cols[start + (i3 < last ? i3 : last)];
    uint4 u0 = XR4[(size_t)s0 * 16 + f];
    uint4 u1 = XR4[(size_t)s1 * 16 + f];
    uint4 u2 = XR4[(size_t)s2 * 16 + f];
    uint4 u3 = XR4[(size_t)s3 * 16 + f];
    uint4 z = make_uint4(0u, 0u, 0u, 0u);
    if (i0 > last) u0 = z;
    if (i1 > last) u1 = z;
    if (i2 > last) u2 = z;
    if (i3 > last) u3 = z;
    accum(u0); accum(u1); accum(u2); accum(u3);
  }

  float s[8] = {a0.x, a0.y, a1.x, a1.y, a2.x, a2.y, a3.x, a3.y};
  #pragma unroll
  for (int j = 0; j < 8; ++j){
    s[j] += __shfl_down(s[j], 32);
    s[j] += __shfl_down(s[j], 16);
  }
  if (q == 0){
    const float4* XL4 = (const float4*)XL;        // row = 32 float4
    float4 xa = XL4[(size_t)node * 32 + 2 * f];
    float4 xb = XL4[(size_t)node * 32 + 2 * f + 1];
    float o0 = xa.x + inv * s[0], o1 = xa.y + inv * s[1];
    float o2 = xa.z + inv * s[2], o3 = xa.w + inv * s[3];
    float o4 = xb.x + inv * s[4], o5 = xb.y + inv * s[5];
    float o6 = xb.z + inv * s[6], o7 = xb.w + inv * s[7];
    if (RELU){
      o0 = fmaxf(o0, 0.f); o1 = fmaxf(o1, 0.f); o2 = fmaxf(o2, 0.f); o3 = fmaxf(o3, 0.f);
      o4 = fmaxf(o4, 0.f); o5 = fmaxf(o5, 0.f); o6 = fmaxf(o6, 0.f); o7 = fmaxf(o7, 0.f);
    }
    uint4 ov;
    ov.x = (unsigned)f2bf(o0) | ((unsigned)f2bf(o1) << 16);
    ov.y = (unsigned)f2bf(o2) | ((unsigned)f2bf(o3) << 16);
    ov.z = (unsigned)f2bf(o4) | ((unsigned)f2bf(o5) << 16);
    ov.w = (unsigned)f2bf(o6) | ((unsigned)f2bf(o7) << 16);
    out[(size_t)node * 16 + f] = ov;
  }
}

// eighth-wave (8 lanes) per 128B row, uint4 loads.
__global__ __launch_bounds__(256) void k_agg64(const int* __restrict__ off,
                                               const int* __restrict__ deg,
                                               const float* __restrict__ invdeg,
                                               const int* __restrict__ cols,
                                               const float* __restrict__ XL,
                                               const u16* __restrict__ XR,
                                               float* __restrict__ out){
  int wave = threadIdx.x >> 6, lane = threadIdx.x & 63;
  int node = blockIdx.x * 4 + wave;
  if (node >= N_NODES) return;
  int start = off[node], cnt = deg[node];
  float inv = invdeg[node];
  int q = lane >> 3, f = lane & 7;
  const uint4* __restrict__ XR4 = (const uint4*)XR;   // row = 8 uint4
  const int* __restrict__ cbase = cols + start + q;

  float2 a0 = make_float2(0.f, 0.f), a1 = a0, a2 = a0, a3 = a0;
  auto accum = [&](uint4 u){
    a0.x += bf2f((u16)(u.x & 0xffffu)); a0.y += bf2f((u16)(u.x >> 16));
    a1.x += bf2f((u16)(u.y & 0xffffu)); a1.y += bf2f((u16)(u.y >> 16));
    a2.x += bf2f((u16)(u.z & 0xffffu)); a2.y += bf2f((u16)(u.z >> 16));
    a3.x += bf2f((u16)(u.w & 0xffffu)); a3.y += bf2f((u16)(u.w >> 16));
  };

  int nfull = cnt & ~15;
  int e = 0;
  for (; e < nfull; e += 16){
    int s0 = cbase[e], s1 = cbase[e + 8];
    uint4 u0 = XR4[(size_t)s0 * 8 + f];
    uint4 u1 = XR4[(size_t)s1 * 8 + f];
    accum(u0); accum(u1);
  }
  if (e < cnt){
    int last = cnt - 1;
    int i0 = e + q, i1 = e + 8 + q;
    int s0 = cols[start + (i0 < last ? i0 : last)];
    int s1 = cols[start + (i1 < last ? i1 : last)];
    uint4 u0 = XR4[(size_t)s0 * 8 + f];
    uint4 u1 = XR4[(size_t)s1 * 8 + f];
    uint4 z = make_uint4(0u, 0u, 0u, 0u);
    if (i0 > last) u0 = z;
    if (i1 > last) u1 = z;
    accum(u0); accum(u1);
  }

  float s[8] = {a0.x, a0.y, a1.x, a1.y, a2.x, a2.y, a3.x, a3.y};
  #pragma unroll
  for (int j = 0; j < 8; ++j){
    s[j] += __shfl_down(s[j], 32);
    s[j] += __shfl_down(s[j], 16);
    s[j] += __shfl_down(s[j], 8);
  }
  if (lane < 8){
    const float4* XL4 = (const float4*)XL;        // row = 16 float4
    float4 xa = XL4[(size_t)node * 16 + 2 * f];
    float4 xb = XL4[(size_t)node * 16 + 2 * f + 1];
    float4 oa, ob;
    oa.x = xa.x + inv * s[0]; oa.y = xa.y + inv * s[1];
    oa.z = xa.z + inv * s[2]; oa.w = xa.w + inv * s[3];
    ob.x = xb.x + inv * s[4]; ob.y = xb.y + inv * s[5];
    ob.z = xb.z + inv * s[6]; ob.w = xb.w + inv * s[7];
    ((float4*)out)[(size_t)node * 16 + 2 * f]     = oa;
    ((float4*)out)[(size_t)node * 16 + 2 * f + 1] = ob;
  }
}

// ---------------- launch ----------------

extern "C" void kernel_launch(void* const* d_in, const int* in_sizes, int n_in,
                              void* d_out, int out_size, void* d_ws, size_t ws_size,
                              hipStream_t stream) {
  const float* x     = (const float*)d_in[0];
  const int*   edges = (const int*)  d_in[1];
  const float* Wl1 = (const float*)d_in[2];
  const float* Wr1 = (const float*)d_in[3];
  const float* b1  = (const float*)d_in[4];
  const float* Wl2 = (const float*)d_in[5];
  const float* Wr2 = (const float*)d_in[6];
  const float* b2  = (const float*)d_in[7];
  const float* Wl3 = (const float*)d_in[8];
  const float* Wr3 = (const float*)d_in[9];
  const float* b3  = (const float*)d_in[10];

  char* ws = (char*)d_ws;
  size_t o = 0;
  auto alloc = [&](size_t bytes) -> void* {
    void* p = ws + o;
    o += (bytes + 255) & ~(size_t)255;
    return p;
  };
  int*   deg    = (int*)  alloc(N_NODES * 4);
  int*   off    = (int*)  alloc(N_NODES * 4);
  float* invdeg = (float*)alloc(N_NODES * 4);
  int*   bcnt   = (int*)  alloc(NBKT * 4);
  int*   bbase  = (int*)  alloc((NBKT + 1) * 4);
  int*   bcur   = (int*)  alloc(NBKT * 4);
  int2*  pairs  = (int2*) alloc((size_t)N_EDGES * 8);
  int*   cols   = (int*)  alloc(N_EDGES * 4);
  u16*   Xb     = (u16*)  alloc((size_t)N_NODES * 128 * 2);
  u16*   XRb    = (u16*)  alloc((size_t)N_NODES * 128 * 2);
  float* XL     = (float*)alloc((size_t)N_NODES * 128 * 4);
  u16*   WT1    = (u16*)  alloc(256 * 128 * 2);
  u16*   WT2    = (u16*)  alloc(256 * 128 * 2);
  u16*   WT3    = (u16*)  alloc(128 * 128 * 2);

  const int AB = (N_EDGES + ACHUNK - 1) / ACHUNK;   // 196

  // fused prep (cast + 3x wprep + bcnt zero) runs first; CSR chain follows
  k_prep<<<CASTB + 256 + 64, 256, 0, stream>>>(x, Xb, Wl1, Wr1, Wl2, Wr2, Wl3, Wr3,
                                               WT1, WT2, WT3, bcnt);
  kA1<<<AB, 256, 0, stream>>>(edges, bcnt);
  k_scanb<<<1, 256, 0, stream>>>(bcnt, bbase, bcur);
  kA2<<<AB, 256, 0, stream>>>(edges, bcur, pairs);
  kB<<<NBKT, 256, 0, stream>>>(pairs, bbase, off, deg, invdeg, cols);

  const int MG = (N_NODES + 63) / 64;         // 782

  // layer 1: 128 -> 128, relu
  { dim3 g(MG, 4); k_gemm<<<g, 256, 0, stream>>>(Xb, WT1, b1, XL, XRb, 128); }
  k_agg128<true><<<(N_NODES + 3) / 4, 256, 0, stream>>>(off, deg, invdeg, cols, XL, XRb, (uint4*)Xb);

  // layer 2: 128 -> 128, relu
  { dim3 g(MG, 4); k_gemm<<<g, 256, 0, stream>>>(Xb, WT2, b2, XL, XRb, 128); }
  k_agg128<true><<<(N_NODES + 3) / 4, 256, 0, stream>>>(off, deg, invdeg, cols, XL, XRb, (uint4*)Xb);

  // layer 3: 128 -> 64, no relu, fp32 out
  { dim3 g(MG, 2); k_gemm<<<g, 256, 0, stream>>>(Xb, WT3, b3, XL, XRb, 64); }
  k_agg64<<<(N_NODES + 3) / 4, 256, 0, stream>>>(off, deg, invdeg, cols, XL, XRb, (float*)d_out);
}

// Round 5
// 257.506 us; speedup vs baseline: 1.8841x; 1.0547x over previous
//
#include <hip/hip_runtime.h>
#include <hip/hip_bf16.h>

#define N_NODES 50000
#define N_EDGES 800000
#define NBKT 196           // ceil(50000/256) buckets of 256 nodes
#define ACHUNK 4096        // edges per block in binning kernels
#define CASTB 6250         // 50000*128/4 float4 chunks / 256 threads

typedef unsigned short u16;
typedef short v8s __attribute__((ext_vector_type(8)));
typedef float v4f __attribute__((ext_vector_type(4)));

__device__ __forceinline__ u16 f2bf(float f){
  union { float f; unsigned u; } x; x.f = f;
  unsigned u = x.u;
  return (u16)((u + 0x7FFFu + ((u >> 16) & 1u)) >> 16);   // RNE
}
__device__ __forceinline__ float lo_bf(unsigned u){
  union { unsigned u; float f; } x; x.u = u << 16; return x.f;
}
__device__ __forceinline__ float hi_bf(unsigned u){
  union { unsigned u; float f; } x; x.u = u & 0xffff0000u; return x.f;
}

// ---------------- fused prep: cast x->bf16, 3x weight transpose, zero bcnt ----

__device__ __forceinline__ void wprep1(const float* __restrict__ Wl,
                                       const float* __restrict__ Wr,
                                       u16* __restrict__ WT, int N1, int idx){
  int n = idx >> 7, k = idx & 127;
  float v = (n < N1) ? Wl[k * N1 + n] : Wr[k * N1 + (n - N1)];
  WT[n * 128 + k] = f2bf(v);
}

__global__ __launch_bounds__(256) void k_prep(const float* __restrict__ x,
                                              u16* __restrict__ Xb,
                                              const float* __restrict__ Wl1,
                                              const float* __restrict__ Wr1,
                                              const float* __restrict__ Wl2,
                                              const float* __restrict__ Wr2,
                                              const float* __restrict__ Wl3,
                                              const float* __restrict__ Wr3,
                                              u16* __restrict__ WT1,
                                              u16* __restrict__ WT2,
                                              u16* __restrict__ WT3,
                                              int* __restrict__ bcnt){
  int b = blockIdx.x, tid = threadIdx.x;
  if (b < CASTB){
    int i = b * 256 + tid;                       // exact: 6250*256 = 1.6M float4
    float4 v = ((const float4*)x)[i];
    ((ushort4*)Xb)[i] = make_ushort4(f2bf(v.x), f2bf(v.y), f2bf(v.z), f2bf(v.w));
  } else if (b < CASTB + 128){
    if (b == CASTB && tid < NBKT) bcnt[tid] = 0;
    wprep1(Wl1, Wr1, WT1, 128, (b - CASTB) * 256 + tid);
  } else if (b < CASTB + 256){
    wprep1(Wl2, Wr2, WT2, 128, (b - CASTB - 128) * 256 + tid);
  } else {
    wprep1(Wl3, Wr3, WT3, 64, (b - CASTB - 256) * 256 + tid);   // 64 blocks
  }
}

// ---------------- CSR build: block-aggregated two-level binning ----------------

__global__ __launch_bounds__(256) void kA1(const int* __restrict__ edges,
                                           int* __restrict__ bcnt){
  __shared__ int h[NBKT];
  int tid = threadIdx.x;
  for (int i = tid; i < NBKT; i += 256) h[i] = 0;
  __syncthreads();
  int base = blockIdx.x * ACHUNK;
  for (int i = tid; i < ACHUNK; i += 256){
    int j = base + i;
    if (j < N_EDGES) atomicAdd(&h[edges[N_EDGES + j] >> 8], 1);
  }
  __syncthreads();
  for (int i = tid; i < NBKT; i += 256)
    if (h[i]) atomicAdd(&bcnt[i], h[i]);
}

__global__ __launch_bounds__(256) void k_scanb(const int* __restrict__ bcnt,
                                               int* __restrict__ bbase,
                                               int* __restrict__ bcur){
  __shared__ int s[256];
  int tid = threadIdx.x;
  int v = (tid < NBKT) ? bcnt[tid] : 0;
  s[tid] = v; __syncthreads();
  for (int d = 1; d < 256; d <<= 1){
    int t = (tid >= d) ? s[tid - d] : 0;
    __syncthreads();
    s[tid] += t;
    __syncthreads();
  }
  if (tid < NBKT){ bbase[tid] = s[tid] - v; bcur[tid] = s[tid] - v; }
  if (tid == NBKT - 1) bbase[NBKT] = s[tid];
}

__global__ __launch_bounds__(256) void kA2(const int* __restrict__ edges,
                                           int* __restrict__ bcur,
                                           int2* __restrict__ pairs){
  __shared__ int h[NBKT];
  int tid = threadIdx.x;
  for (int i = tid; i < NBKT; i += 256) h[i] = 0;
  __syncthreads();
  int base = blockIdx.x * ACHUNK;
  for (int i = tid; i < ACHUNK; i += 256){
    int j = base + i;
    if (j < N_EDGES) atomicAdd(&h[edges[N_EDGES + j] >> 8], 1);
  }
  __syncthreads();
  for (int i = tid; i < NBKT; i += 256)
    h[i] = h[i] ? atomicAdd(&bcur[i], h[i]) : 0;   // h becomes block-local cursor
  __syncthreads();
  for (int i = tid; i < ACHUNK; i += 256){
    int j = base + i;
    if (j < N_EDGES){
      int s = edges[j], d = edges[N_EDGES + j];
      int pos = atomicAdd(&h[d >> 8], 1);
      pairs[pos] = make_int2(s, d);
    }
  }
}

__global__ __launch_bounds__(256) void kB(const int2* __restrict__ pairs,
                                          const int* __restrict__ bbase,
                                          int* __restrict__ off,
                                          int* __restrict__ deg,
                                          float* __restrict__ invdeg,
                                          int* __restrict__ cols){
  __shared__ int h[256];
  __shared__ int s[256];
  __shared__ int cur[256];
  int tid = threadIdx.x;
  int bkt = blockIdx.x;
  int base = bbase[bkt], cnt = bbase[bkt + 1] - base;
  int nodeBase = bkt << 8;

  h[tid] = 0; __syncthreads();
  for (int i = tid; i < cnt; i += 256){
    int2 p = pairs[base + i];
    atomicAdd(&h[p.y - nodeBase], 1);
  }
  __syncthreads();
  int v = h[tid];
  s[tid] = v; __syncthreads();
  for (int d = 1; d < 256; d <<= 1){
    int t = (tid >= d) ? s[tid - d] : 0;
    __syncthreads();
    s[tid] += t;
    __syncthreads();
  }
  int excl = s[tid] - v;
  int node = nodeBase + tid;
  if (node < N_NODES){
    off[node] = base + excl;
    deg[node] = v;
    invdeg[node] = 1.0f / (float)(v > 1 ? v : 1);
  }
  cur[tid] = base + excl;
  __syncthreads();
  for (int i = tid; i < cnt; i += 256){
    int2 p = pairs[base + i];
    int pos = atomicAdd(&cur[p.y - nodeBase], 1);
    cols[pos] = p.x;
  }
}

// ---------------- fused GEMM: XL = A@Wl + b (fp32), XR = A@Wr (bf16) ----------------
// A staged once per block; col-phases loop re-stages Bs (WT is L2-hot, 64 KB).

__global__ __launch_bounds__(256) void k_gemm(const u16* __restrict__ A,
                                              const u16* __restrict__ WT,
                                              const float* __restrict__ bias,
                                              float* __restrict__ XL,
                                              u16* __restrict__ XR, int N1){
  __shared__ u16 As[64 * 136];
  __shared__ u16 Bs[64 * 136];
  const int tid = threadIdx.x;
  const int rowBase = blockIdx.x * 64;

  // stage A tile (64x128) once
  #pragma unroll
  for (int it = 0; it < 4; ++it){
    int chunk = tid + it * 256;
    int r = chunk >> 4, cseg = chunk & 15;
    int gr = rowBase + r;
    uint4 va = make_uint4(0u, 0u, 0u, 0u);
    if (gr < N_NODES) va = ((const uint4*)(A + (size_t)gr * 128))[cseg];
    ((uint4*)As)[r * 17 + cseg] = va;
  }

  const int lane = tid & 63, wave = tid >> 6;
  const int quad = lane >> 4, l15 = lane & 15;
  const int wm = wave & 1, wn = wave >> 1;
  const int nph = N1 >> 5;                       // (2*N1)/64 phases

  for (int p = 0; p < nph; ++p){
    int colBase = p * 64;
    #pragma unroll
    for (int it = 0; it < 4; ++it){
      int chunk = tid + it * 256;
      int r = chunk >> 4, cseg = chunk & 15;
      ((uint4*)Bs)[r * 17 + cseg] = ((const uint4*)(WT + (size_t)(colBase + r) * 128))[cseg];
    }
    __syncthreads();

    v4f acc[2][2] = {};
    #pragma unroll
    for (int kt = 0; kt < 4; ++kt){
      int ko = kt * 32 + quad * 8;
      v8s a0 = *(const v8s*)&As[(wm * 32 + l15) * 136 + ko];
      v8s a1 = *(const v8s*)&As[(wm * 32 + 16 + l15) * 136 + ko];
      v8s b0 = *(const v8s*)&Bs[(wn * 32 + l15) * 136 + ko];
      v8s b1 = *(const v8s*)&Bs[(wn * 32 + 16 + l15) * 136 + ko];
      acc[0][0] = __builtin_amdgcn_mfma_f32_16x16x32_bf16(a0, b0, acc[0][0], 0, 0, 0);
      acc[0][1] = __builtin_amdgcn_mfma_f32_16x16x32_bf16(a0, b1, acc[0][1], 0, 0, 0);
      acc[1][0] = __builtin_amdgcn_mfma_f32_16x16x32_bf16(a1, b0, acc[1][0], 0, 0, 0);
      acc[1][1] = __builtin_amdgcn_mfma_f32_16x16x32_bf16(a1, b1, acc[1][1], 0, 0, 0);
    }

    #pragma unroll
    for (int mi = 0; mi < 2; ++mi)
      #pragma unroll
      for (int ni = 0; ni < 2; ++ni)
        #pragma unroll
        for (int r = 0; r < 4; ++r){
          int grow = rowBase + wm * 32 + mi * 16 + quad * 4 + r;
          int gcol = colBase + wn * 32 + ni * 16 + l15;
          if (grow < N_NODES){
            float v = acc[mi][ni][r];
            if (gcol < N1) XL[(size_t)grow * N1 + gcol] = v + bias[gcol];
            else           XR[(size_t)grow * N1 + (gcol - N1)] = f2bf(v);
          }
        }
    __syncthreads();
  }
}

// ---------------- aggregate + combine (+ReLU, +cast) ----------------
// quarter-wave (16 lanes) per NODE: no reduction shuffles, exact per-edge loads,
// 16 nodes/block. 50000 = 3125*16 -> no bounds check.

template<bool RELU>
__global__ __launch_bounds__(256) void k_agg128(const int* __restrict__ off,
                                                const int* __restrict__ deg,
                                                const float* __restrict__ invdeg,
                                                const int* __restrict__ cols,
                                                const float* __restrict__ XL,
                                                const u16* __restrict__ XR,
                                                uint4* __restrict__ out){
  int tid = threadIdx.x;
  int qq = tid >> 4, f = tid & 15;
  int node = blockIdx.x * 16 + qq;
  int start = off[node], cnt = deg[node];
  float inv = invdeg[node];
  const uint4* __restrict__ XR4 = (const uint4*)XR;   // row = 16 uint4
  const int* __restrict__ cb = cols + start;

  float2 a0 = make_float2(0.f, 0.f), a1 = a0, a2 = a0, a3 = a0;
  auto accum = [&](uint4 u){
    a0.x += lo_bf(u.x); a0.y += hi_bf(u.x);
    a1.x += lo_bf(u.y); a1.y += hi_bf(u.y);
    a2.x += lo_bf(u.z); a2.y += hi_bf(u.z);
    a3.x += lo_bf(u.w); a3.y += hi_bf(u.w);
  };

  int e = 0;
  for (; e + 4 <= cnt; e += 4){
    int s0 = cb[e], s1 = cb[e + 1], s2 = cb[e + 2], s3 = cb[e + 3];
    uint4 u0 = XR4[(size_t)s0 * 16 + f];
    uint4 u1 = XR4[(size_t)s1 * 16 + f];
    uint4 u2 = XR4[(size_t)s2 * 16 + f];
    uint4 u3 = XR4[(size_t)s3 * 16 + f];
    accum(u0); accum(u1); accum(u2); accum(u3);
  }
  if (e < cnt){                                   // masked 4-granule tail (<=1 iter)
    int last = cnt - 1;
    int i1 = e + 1 < last ? e + 1 : last;
    int i2 = e + 2 < last ? e + 2 : last;
    int i3 = e + 3 < last ? e + 3 : last;
    int s0 = cb[e], s1 = cb[i1], s2 = cb[i2], s3 = cb[i3];
    uint4 u0 = XR4[(size_t)s0 * 16 + f];
    uint4 u1 = XR4[(size_t)s1 * 16 + f];
    uint4 u2 = XR4[(size_t)s2 * 16 + f];
    uint4 u3 = XR4[(size_t)s3 * 16 + f];
    uint4 z = make_uint4(0u, 0u, 0u, 0u);
    if (e + 1 > last) u1 = z;
    if (e + 2 > last) u2 = z;
    if (e + 3 > last) u3 = z;
    accum(u0); accum(u1); accum(u2); accum(u3);
  }

  const float4* __restrict__ XL4 = (const float4*)XL; // row = 32 float4
  float4 xa = XL4[(size_t)node * 32 + 2 * f];
  float4 xb = XL4[(size_t)node * 32 + 2 * f + 1];
  float o0 = xa.x + inv * a0.x, o1 = xa.y + inv * a0.y;
  float o2 = xa.z + inv * a1.x, o3 = xa.w + inv * a1.y;
  float o4 = xb.x + inv * a2.x, o5 = xb.y + inv * a2.y;
  float o6 = xb.z + inv * a3.x, o7 = xb.w + inv * a3.y;
  if (RELU){
    o0 = fmaxf(o0, 0.f); o1 = fmaxf(o1, 0.f); o2 = fmaxf(o2, 0.f); o3 = fmaxf(o3, 0.f);
    o4 = fmaxf(o4, 0.f); o5 = fmaxf(o5, 0.f); o6 = fmaxf(o6, 0.f); o7 = fmaxf(o7, 0.f);
  }
  uint4 ov;
  ov.x = (unsigned)f2bf(o0) | ((unsigned)f2bf(o1) << 16);
  ov.y = (unsigned)f2bf(o2) | ((unsigned)f2bf(o3) << 16);
  ov.z = (unsigned)f2bf(o4) | ((unsigned)f2bf(o5) << 16);
  ov.w = (unsigned)f2bf(o6) | ((unsigned)f2bf(o7) << 16);
  out[(size_t)node * 16 + f] = ov;
}

// eighth-wave (8 lanes) per node, row = 8 uint4; 32 nodes/block.
__global__ __launch_bounds__(256) void k_agg64(const int* __restrict__ off,
                                               const int* __restrict__ deg,
                                               const float* __restrict__ invdeg,
                                               const int* __restrict__ cols,
                                               const float* __restrict__ XL,
                                               const u16* __restrict__ XR,
                                               float* __restrict__ out){
  int tid = threadIdx.x;
  int oo = tid >> 3, f = tid & 7;
  int node = blockIdx.x * 32 + oo;
  if (node >= N_NODES) return;
  int start = off[node], cnt = deg[node];
  float inv = invdeg[node];
  const uint4* __restrict__ XR4 = (const uint4*)XR;   // row = 8 uint4
  const int* __restrict__ cb = cols + start;

  float2 a0 = make_float2(0.f, 0.f), a1 = a0, a2 = a0, a3 = a0;
  auto accum = [&](uint4 u){
    a0.x += lo_bf(u.x); a0.y += hi_bf(u.x);
    a1.x += lo_bf(u.y); a1.y += hi_bf(u.y);
    a2.x += lo_bf(u.z); a2.y += hi_bf(u.z);
    a3.x += lo_bf(u.w); a3.y += hi_bf(u.w);
  };

  int e = 0;
  for (; e + 4 <= cnt; e += 4){
    int s0 = cb[e], s1 = cb[e + 1], s2 = cb[e + 2], s3 = cb[e + 3];
    uint4 u0 = XR4[(size_t)s0 * 8 + f];
    uint4 u1 = XR4[(size_t)s1 * 8 + f];
    uint4 u2 = XR4[(size_t)s2 * 8 + f];
    uint4 u3 = XR4[(size_t)s3 * 8 + f];
    accum(u0); accum(u1); accum(u2); accum(u3);
  }
  if (e < cnt){
    int last = cnt - 1;
    int i1 = e + 1 < last ? e + 1 : last;
    int i2 = e + 2 < last ? e + 2 : last;
    int i3 = e + 3 < last ? e + 3 : last;
    int s0 = cb[e], s1 = cb[i1], s2 = cb[i2], s3 = cb[i3];
    uint4 u0 = XR4[(size_t)s0 * 8 + f];
    uint4 u1 = XR4[(size_t)s1 * 8 + f];
    uint4 u2 = XR4[(size_t)s2 * 8 + f];
    uint4 u3 = XR4[(size_t)s3 * 8 + f];
    uint4 z = make_uint4(0u, 0u, 0u, 0u);
    if (e + 1 > last) u1 = z;
    if (e + 2 > last) u2 = z;
    if (e + 3 > last) u3 = z;
    accum(u0); accum(u1); accum(u2); accum(u3);
  }

  const float4* __restrict__ XL4 = (const float4*)XL; // row = 16 float4
  float4 xa = XL4[(size_t)node * 16 + 2 * f];
  float4 xb = XL4[(size_t)node * 16 + 2 * f + 1];
  float4 oa, ob;
  oa.x = xa.x + inv * a0.x; oa.y = xa.y + inv * a0.y;
  oa.z = xa.z + inv * a1.x; oa.w = xa.w + inv * a1.y;
  ob.x = xb.x + inv * a2.x; ob.y = xb.y + inv * a2.y;
  ob.z = xb.z + inv * a3.x; ob.w = xb.w + inv * a3.y;
  ((float4*)out)[(size_t)node * 16 + 2 * f]     = oa;
  ((float4*)out)[(size_t)node * 16 + 2 * f + 1] = ob;
}

// ---------------- launch ----------------

extern "C" void kernel_launch(void* const* d_in, const int* in_sizes, int n_in,
                              void* d_out, int out_size, void* d_ws, size_t ws_size,
                              hipStream_t stream) {
  const float* x     = (const float*)d_in[0];
  const int*   edges = (const int*)  d_in[1];
  const float* Wl1 = (const float*)d_in[2];
  const float* Wr1 = (const float*)d_in[3];
  const float* b1  = (const float*)d_in[4];
  const float* Wl2 = (const float*)d_in[5];
  const float* Wr2 = (const float*)d_in[6];
  const float* b2  = (const float*)d_in[7];
  const float* Wl3 = (const float*)d_in[8];
  const float* Wr3 = (const float*)d_in[9];
  const float* b3  = (const float*)d_in[10];

  char* ws = (char*)d_ws;
  size_t o = 0;
  auto alloc = [&](size_t bytes) -> void* {
    void* p = ws + o;
    o += (bytes + 255) & ~(size_t)255;
    return p;
  };
  int*   deg    = (int*)  alloc(N_NODES * 4);
  int*   off    = (int*)  alloc(N_NODES * 4);
  float* invdeg = (float*)alloc(N_NODES * 4);
  int*   bcnt   = (int*)  alloc(NBKT * 4);
  int*   bbase  = (int*)  alloc((NBKT + 1) * 4);
  int*   bcur   = (int*)  alloc(NBKT * 4);
  int2*  pairs  = (int2*) alloc((size_t)N_EDGES * 8);
  int*   cols   = (int*)  alloc(N_EDGES * 4);
  u16*   Xb     = (u16*)  alloc((size_t)N_NODES * 128 * 2);
  u16*   XRb    = (u16*)  alloc((size_t)N_NODES * 128 * 2);
  float* XL     = (float*)alloc((size_t)N_NODES * 128 * 4);
  u16*   WT1    = (u16*)  alloc(256 * 128 * 2);
  u16*   WT2    = (u16*)  alloc(256 * 128 * 2);
  u16*   WT3    = (u16*)  alloc(128 * 128 * 2);

  const int AB = (N_EDGES + ACHUNK - 1) / ACHUNK;   // 196

  // fused prep (cast + 3x wprep + bcnt zero) runs first; CSR chain follows
  k_prep<<<CASTB + 256 + 64, 256, 0, stream>>>(x, Xb, Wl1, Wr1, Wl2, Wr2, Wl3, Wr3,
                                               WT1, WT2, WT3, bcnt);
  kA1<<<AB, 256, 0, stream>>>(edges, bcnt);
  k_scanb<<<1, 256, 0, stream>>>(bcnt, bbase, bcur);
  kA2<<<AB, 256, 0, stream>>>(edges, bcur, pairs);
  kB<<<NBKT, 256, 0, stream>>>(pairs, bbase, off, deg, invdeg, cols);

  const int MG = (N_NODES + 63) / 64;         // 782

  // layer 1: 128 -> 128, relu
  k_gemm<<<MG, 256, 0, stream>>>(Xb, WT1, b1, XL, XRb, 128);
  k_agg128<true><<<N_NODES / 16, 256, 0, stream>>>(off, deg, invdeg, cols, XL, XRb, (uint4*)Xb);

  // layer 2: 128 -> 128, relu
  k_gemm<<<MG, 256, 0, stream>>>(Xb, WT2, b2, XL, XRb, 128);
  k_agg128<true><<<N_NODES / 16, 256, 0, stream>>>(off, deg, invdeg, cols, XL, XRb, (uint4*)Xb);

  // layer 3: 128 -> 64, no relu, fp32 out
  k_gemm<<<MG, 256, 0, stream>>>(Xb, WT3, b3, XL, XRb, 64);
  k_agg64<<<(N_NODES + 31) / 32, 256, 0, stream>>>(off, deg, invdeg, cols, XL, XRb, (float*)d_out);
}

// Round 6
// 246.633 us; speedup vs baseline: 1.9672x; 1.0441x over previous
//
#include <hip/hip_runtime.h>
#include <hip/hip_bf16.h>

#define N_NODES 50000
#define N_EDGES 800000
#define NBKT 196           // ceil(50000/256) buckets of 256 nodes
#define ACHUNK 4096        // edges per block in binning kernels
#define AB 196             // ceil(800000/4096) histogram blocks
#define CASTB 6250         // 50000*128/4 float4 chunks / 256 threads
#define MG 782             // ceil(50000/64) gemm row-tiles

typedef unsigned short u16;
typedef short v8s __attribute__((ext_vector_type(8)));
typedef float v4f __attribute__((ext_vector_type(4)));

__device__ __forceinline__ u16 f2bf(float f){
  union { float f; unsigned u; } x; x.f = f;
  unsigned u = x.u;
  return (u16)((u + 0x7FFFu + ((u >> 16) & 1u)) >> 16);   // RNE
}
__device__ __forceinline__ float lo_bf(unsigned u){
  union { unsigned u; float f; } x; x.u = u << 16; return x.f;
}
__device__ __forceinline__ float hi_bf(unsigned u){
  union { unsigned u; float f; } x; x.u = u & 0xffff0000u; return x.f;
}

// ---------------- fused prep: cast x->bf16, 3x weight transpose, A1 partial hists

__device__ __forceinline__ void wprep1(const float* __restrict__ Wl,
                                       const float* __restrict__ Wr,
                                       u16* __restrict__ WT, int N1, int idx){
  int n = idx >> 7, k = idx & 127;
  float v = (n < N1) ? Wl[k * N1 + n] : Wr[k * N1 + (n - N1)];
  WT[n * 128 + k] = f2bf(v);
}

__global__ __launch_bounds__(256) void k_prep_a1(const float* __restrict__ x,
                                                 u16* __restrict__ Xb,
                                                 const float* __restrict__ Wl1,
                                                 const float* __restrict__ Wr1,
                                                 const float* __restrict__ Wl2,
                                                 const float* __restrict__ Wr2,
                                                 const float* __restrict__ Wl3,
                                                 const float* __restrict__ Wr3,
                                                 u16* __restrict__ WT1,
                                                 u16* __restrict__ WT2,
                                                 u16* __restrict__ WT3,
                                                 const int* __restrict__ edges,
                                                 int* __restrict__ bpart){
  __shared__ int h[NBKT];
  int b = blockIdx.x, tid = threadIdx.x;
  if (b < CASTB){
    int i = b * 256 + tid;                       // exact: 6250*256 = 1.6M float4
    float4 v = ((const float4*)x)[i];
    ((ushort4*)Xb)[i] = make_ushort4(f2bf(v.x), f2bf(v.y), f2bf(v.z), f2bf(v.w));
  } else if (b < CASTB + 128){
    wprep1(Wl1, Wr1, WT1, 128, (b - CASTB) * 256 + tid);
  } else if (b < CASTB + 256){
    wprep1(Wl2, Wr2, WT2, 128, (b - CASTB - 128) * 256 + tid);
  } else if (b < CASTB + 320){
    wprep1(Wl3, Wr3, WT3, 64, (b - CASTB - 256) * 256 + tid);   // 64 blocks
  } else {
    int ab = b - (CASTB + 320);                  // 0..AB-1
    for (int i = tid; i < NBKT; i += 256) h[i] = 0;
    __syncthreads();
    int base = ab * ACHUNK;
    for (int i = tid; i < ACHUNK; i += 256){
      int j = base + i;
      if (j < N_EDGES) atomicAdd(&h[edges[N_EDGES + j] >> 8], 1);
    }
    __syncthreads();
    for (int i = tid; i < NBKT; i += 256) bpart[ab * NBKT + i] = h[i];
  }
}

// reduce partial hists + scan -> bbase (exclusive, +total), init bcur
__global__ __launch_bounds__(256) void k_scanb(const int* __restrict__ bpart,
                                               int* __restrict__ bbase,
                                               int* __restrict__ bcur){
  __shared__ int s[256];
  int tid = threadIdx.x;
  int v = 0;
  if (tid < NBKT){
    int a0 = 0, a1 = 0, a2 = 0, a3 = 0;
    int r = 0;
    for (; r + 4 <= AB; r += 4){
      a0 += bpart[(r    ) * NBKT + tid];
      a1 += bpart[(r + 1) * NBKT + tid];
      a2 += bpart[(r + 2) * NBKT + tid];
      a3 += bpart[(r + 3) * NBKT + tid];
    }
    for (; r < AB; ++r) a0 += bpart[r * NBKT + tid];
    v = (a0 + a1) + (a2 + a3);
  }
  s[tid] = v; __syncthreads();
  for (int d = 1; d < 256; d <<= 1){
    int t = (tid >= d) ? s[tid - d] : 0;
    __syncthreads();
    s[tid] += t;
    __syncthreads();
  }
  if (tid < NBKT){ bbase[tid] = s[tid] - v; bcur[tid] = s[tid] - v; }
  if (tid == NBKT - 1) bbase[NBKT] = s[tid];
}

__global__ __launch_bounds__(256) void kA2(const int* __restrict__ edges,
                                           int* __restrict__ bcur,
                                           int2* __restrict__ pairs){
  __shared__ int h[NBKT];
  int tid = threadIdx.x;
  for (int i = tid; i < NBKT; i += 256) h[i] = 0;
  __syncthreads();
  int base = blockIdx.x * ACHUNK;
  for (int i = tid; i < ACHUNK; i += 256){
    int j = base + i;
    if (j < N_EDGES) atomicAdd(&h[edges[N_EDGES + j] >> 8], 1);
  }
  __syncthreads();
  for (int i = tid; i < NBKT; i += 256)
    h[i] = h[i] ? atomicAdd(&bcur[i], h[i]) : 0;   // h becomes block-local cursor
  __syncthreads();
  for (int i = tid; i < ACHUNK; i += 256){
    int j = base + i;
    if (j < N_EDGES){
      int s = edges[j], d = edges[N_EDGES + j];
      int pos = atomicAdd(&h[d >> 8], 1);
      pairs[pos] = make_int2(s, d);
    }
  }
}

// ---------------- kB body (bucket counting sort) + gemm body --------------------

__device__ __forceinline__ void kB_body(int bkt, int tid,
                                        const int2* __restrict__ pairs,
                                        const int* __restrict__ bbase,
                                        int* __restrict__ off,
                                        int* __restrict__ deg,
                                        float* __restrict__ invdeg,
                                        int* __restrict__ cols,
                                        int* h, int* s, int* cur){
  int base = bbase[bkt], cnt = bbase[bkt + 1] - base;
  int nodeBase = bkt << 8;

  h[tid] = 0; __syncthreads();
  for (int i = tid; i < cnt; i += 256){
    int2 p = pairs[base + i];
    atomicAdd(&h[p.y - nodeBase], 1);
  }
  __syncthreads();
  int v = h[tid];
  s[tid] = v; __syncthreads();
  for (int d = 1; d < 256; d <<= 1){
    int t = (tid >= d) ? s[tid - d] : 0;
    __syncthreads();
    s[tid] += t;
    __syncthreads();
  }
  int excl = s[tid] - v;
  int node = nodeBase + tid;
  if (node < N_NODES){
    off[node] = base + excl;
    deg[node] = v;
    invdeg[node] = 1.0f / (float)(v > 1 ? v : 1);
  }
  cur[tid] = base + excl;
  __syncthreads();
  for (int i = tid; i < cnt; i += 256){
    int2 p = pairs[base + i];
    int pos = atomicAdd(&cur[p.y - nodeBase], 1);
    cols[pos] = p.x;
  }
}

// fused GEMM: XLb = bf16(A@Wl + b), XR = bf16(A@Wr). A staged once; B per phase.
__device__ __forceinline__ void gemm_body(int blk, int tid,
                                          const u16* __restrict__ A,
                                          const u16* __restrict__ WT,
                                          const float* __restrict__ bias,
                                          u16* __restrict__ XLb,
                                          u16* __restrict__ XR, int N1,
                                          u16* As, u16* Bs){
  const int rowBase = blk * 64;

  #pragma unroll
  for (int it = 0; it < 4; ++it){
    int chunk = tid + it * 256;
    int r = chunk >> 4, cseg = chunk & 15;
    int gr = rowBase + r;
    uint4 va = make_uint4(0u, 0u, 0u, 0u);
    if (gr < N_NODES) va = ((const uint4*)(A + (size_t)gr * 128))[cseg];
    ((uint4*)As)[r * 17 + cseg] = va;
  }

  const int lane = tid & 63, wave = tid >> 6;
  const int quad = lane >> 4, l15 = lane & 15;
  const int wm = wave & 1, wn = wave >> 1;
  const int nph = N1 >> 5;                       // (2*N1)/64 phases

  for (int p = 0; p < nph; ++p){
    int colBase = p * 64;
    #pragma unroll
    for (int it = 0; it < 4; ++it){
      int chunk = tid + it * 256;
      int r = chunk >> 4, cseg = chunk & 15;
      ((uint4*)Bs)[r * 17 + cseg] = ((const uint4*)(WT + (size_t)(colBase + r) * 128))[cseg];
    }
    __syncthreads();

    v4f acc[2][2] = {};
    #pragma unroll
    for (int kt = 0; kt < 4; ++kt){
      int ko = kt * 32 + quad * 8;
      v8s a0 = *(const v8s*)&As[(wm * 32 + l15) * 136 + ko];
      v8s a1 = *(const v8s*)&As[(wm * 32 + 16 + l15) * 136 + ko];
      v8s b0 = *(const v8s*)&Bs[(wn * 32 + l15) * 136 + ko];
      v8s b1 = *(const v8s*)&Bs[(wn * 32 + 16 + l15) * 136 + ko];
      acc[0][0] = __builtin_amdgcn_mfma_f32_16x16x32_bf16(a0, b0, acc[0][0], 0, 0, 0);
      acc[0][1] = __builtin_amdgcn_mfma_f32_16x16x32_bf16(a0, b1, acc[0][1], 0, 0, 0);
      acc[1][0] = __builtin_amdgcn_mfma_f32_16x16x32_bf16(a1, b0, acc[1][0], 0, 0, 0);
      acc[1][1] = __builtin_amdgcn_mfma_f32_16x16x32_bf16(a1, b1, acc[1][1], 0, 0, 0);
    }

    #pragma unroll
    for (int mi = 0; mi < 2; ++mi)
      #pragma unroll
      for (int ni = 0; ni < 2; ++ni)
        #pragma unroll
        for (int r = 0; r < 4; ++r){
          int grow = rowBase + wm * 32 + mi * 16 + quad * 4 + r;
          int gcol = colBase + wn * 32 + ni * 16 + l15;
          if (grow < N_NODES){
            float v = acc[mi][ni][r];
            if (gcol < N1) XLb[(size_t)grow * N1 + gcol] = f2bf(v + bias[gcol]);
            else           XR[(size_t)grow * N1 + (gcol - N1)] = f2bf(v);
          }
        }
    __syncthreads();
  }
}

__global__ __launch_bounds__(256) void k_kb_gemm(const int2* __restrict__ pairs,
                                                 const int* __restrict__ bbase,
                                                 int* __restrict__ off,
                                                 int* __restrict__ deg,
                                                 float* __restrict__ invdeg,
                                                 int* __restrict__ cols,
                                                 const u16* __restrict__ A,
                                                 const u16* __restrict__ WT,
                                                 const float* __restrict__ bias,
                                                 u16* __restrict__ XLb,
                                                 u16* __restrict__ XR){
  __shared__ u16 As[64 * 136];
  __shared__ u16 Bs[64 * 136];
  int tid = threadIdx.x;
  if (blockIdx.x < NBKT){
    int* h = (int*)As;                 // 3 KB aliased into As
    kB_body(blockIdx.x, tid, pairs, bbase, off, deg, invdeg, cols,
            h, h + 256, h + 512);
  } else {
    gemm_body(blockIdx.x - NBKT, tid, A, WT, bias, XLb, XR, 128, As, Bs);
  }
}

__global__ __launch_bounds__(256) void k_gemm(const u16* __restrict__ A,
                                              const u16* __restrict__ WT,
                                              const float* __restrict__ bias,
                                              u16* __restrict__ XLb,
                                              u16* __restrict__ XR, int N1){
  __shared__ u16 As[64 * 136];
  __shared__ u16 Bs[64 * 136];
  gemm_body(blockIdx.x, threadIdx.x, A, WT, bias, XLb, XR, N1, As, Bs);
}

// ---------------- aggregate + combine (+ReLU, +cast) ----------------
// quarter-wave (16 lanes) per NODE; 8 uint4 gathers in flight per thread.

template<bool RELU>
__global__ __launch_bounds__(256) void k_agg128(const int* __restrict__ off,
                                                const int* __restrict__ deg,
                                                const float* __restrict__ invdeg,
                                                const int* __restrict__ cols,
                                                const u16* __restrict__ XLb,
                                                const u16* __restrict__ XR,
                                                uint4* __restrict__ out){
  int tid = threadIdx.x;
  int qq = tid >> 4, f = tid & 15;
  int node = blockIdx.x * 16 + qq;              // 50000 = 3125*16, no bound check
  int start = off[node], cnt = deg[node];
  float inv = invdeg[node];
  const uint4* __restrict__ XR4 = (const uint4*)XR;   // row = 16 uint4
  const int* __restrict__ cb = cols + start;

  float2 a0 = make_float2(0.f, 0.f), a1 = a0, a2 = a0, a3 = a0;
  auto accum = [&](uint4 u){
    a0.x += lo_bf(u.x); a0.y += hi_bf(u.x);
    a1.x += lo_bf(u.y); a1.y += hi_bf(u.y);
    a2.x += lo_bf(u.z); a2.y += hi_bf(u.z);
    a3.x += lo_bf(u.w); a3.y += hi_bf(u.w);
  };

  int e = 0;
  int nfull = cnt & ~7;
  for (; e < nfull; e += 8){
    int s[8];
    #pragma unroll
    for (int j = 0; j < 8; ++j) s[j] = cb[e + j];
    uint4 u[8];
    #pragma unroll
    for (int j = 0; j < 8; ++j) u[j] = XR4[(size_t)s[j] * 16 + f];
    #pragma unroll
    for (int j = 0; j < 8; ++j) accum(u[j]);
  }
  if (e < cnt){                                 // masked 8-granule tail (<=1 iter)
    int last = cnt - 1;
    int s[8];
    #pragma unroll
    for (int j = 0; j < 8; ++j){
      int i = e + j;
      s[j] = cb[i < last ? i : last];
    }
    uint4 u[8];
    #pragma unroll
    for (int j = 0; j < 8; ++j) u[j] = XR4[(size_t)s[j] * 16 + f];
    #pragma unroll
    for (int j = 0; j < 8; ++j){
      if (e + j > last) u[j] = make_uint4(0u, 0u, 0u, 0u);
      accum(u[j]);
    }
  }

  uint4 xl = ((const uint4*)XLb)[(size_t)node * 16 + f];
  float o0 = lo_bf(xl.x) + inv * a0.x, o1 = hi_bf(xl.x) + inv * a0.y;
  float o2 = lo_bf(xl.y) + inv * a1.x, o3 = hi_bf(xl.y) + inv * a1.y;
  float o4 = lo_bf(xl.z) + inv * a2.x, o5 = hi_bf(xl.z) + inv * a2.y;
  float o6 = lo_bf(xl.w) + inv * a3.x, o7 = hi_bf(xl.w) + inv * a3.y;
  if (RELU){
    o0 = fmaxf(o0, 0.f); o1 = fmaxf(o1, 0.f); o2 = fmaxf(o2, 0.f); o3 = fmaxf(o3, 0.f);
    o4 = fmaxf(o4, 0.f); o5 = fmaxf(o5, 0.f); o6 = fmaxf(o6, 0.f); o7 = fmaxf(o7, 0.f);
  }
  uint4 ov;
  ov.x = (unsigned)f2bf(o0) | ((unsigned)f2bf(o1) << 16);
  ov.y = (unsigned)f2bf(o2) | ((unsigned)f2bf(o3) << 16);
  ov.z = (unsigned)f2bf(o4) | ((unsigned)f2bf(o5) << 16);
  ov.w = (unsigned)f2bf(o6) | ((unsigned)f2bf(o7) << 16);
  out[(size_t)node * 16 + f] = ov;
}

// eighth-wave (8 lanes) per node, row = 8 uint4; fp32 out.
__global__ __launch_bounds__(256) void k_agg64(const int* __restrict__ off,
                                               const int* __restrict__ deg,
                                               const float* __restrict__ invdeg,
                                               const int* __restrict__ cols,
                                               const u16* __restrict__ XLb,
                                               const u16* __restrict__ XR,
                                               float* __restrict__ out){
  int tid = threadIdx.x;
  int oo = tid >> 3, f = tid & 7;
  int node = blockIdx.x * 32 + oo;
  if (node >= N_NODES) return;
  int start = off[node], cnt = deg[node];
  float inv = invdeg[node];
  const uint4* __restrict__ XR4 = (const uint4*)XR;   // row = 8 uint4
  const int* __restrict__ cb = cols + start;

  float2 a0 = make_float2(0.f, 0.f), a1 = a0, a2 = a0, a3 = a0;
  auto accum = [&](uint4 u){
    a0.x += lo_bf(u.x); a0.y += hi_bf(u.x);
    a1.x += lo_bf(u.y); a1.y += hi_bf(u.y);
    a2.x += lo_bf(u.z); a2.y += hi_bf(u.z);
    a3.x += lo_bf(u.w); a3.y += hi_bf(u.w);
  };

  int e = 0;
  int nfull = cnt & ~7;
  for (; e < nfull; e += 8){
    int s[8];
    #pragma unroll
    for (int j = 0; j < 8; ++j) s[j] = cb[e + j];
    uint4 u[8];
    #pragma unroll
    for (int j = 0; j < 8; ++j) u[j] = XR4[(size_t)s[j] * 8 + f];
    #pragma unroll
    for (int j = 0; j < 8; ++j) accum(u[j]);
  }
  if (e < cnt){
    int last = cnt - 1;
    int s[8];
    #pragma unroll
    for (int j = 0; j < 8; ++j){
      int i = e + j;
      s[j] = cb[i < last ? i : last];
    }
    uint4 u[8];
    #pragma unroll
    for (int j = 0; j < 8; ++j) u[j] = XR4[(size_t)s[j] * 8 + f];
    #pragma unroll
    for (int j = 0; j < 8; ++j){
      if (e + j > last) u[j] = make_uint4(0u, 0u, 0u, 0u);
      accum(u[j]);
    }
  }

  uint4 xl = ((const uint4*)XLb)[(size_t)node * 8 + f];
  float4 oa, ob;
  oa.x = lo_bf(xl.x) + inv * a0.x; oa.y = hi_bf(xl.x) + inv * a0.y;
  oa.z = lo_bf(xl.y) + inv * a1.x; oa.w = hi_bf(xl.y) + inv * a1.y;
  ob.x = lo_bf(xl.z) + inv * a2.x; ob.y = hi_bf(xl.z) + inv * a2.y;
  ob.z = lo_bf(xl.w) + inv * a3.x; ob.w = hi_bf(xl.w) + inv * a3.y;
  ((float4*)out)[(size_t)node * 16 + 2 * f]     = oa;
  ((float4*)out)[(size_t)node * 16 + 2 * f + 1] = ob;
}

// ---------------- launch ----------------

extern "C" void kernel_launch(void* const* d_in, const int* in_sizes, int n_in,
                              void* d_out, int out_size, void* d_ws, size_t ws_size,
                              hipStream_t stream) {
  const float* x     = (const float*)d_in[0];
  const int*   edges = (const int*)  d_in[1];
  const float* Wl1 = (const float*)d_in[2];
  const float* Wr1 = (const float*)d_in[3];
  const float* b1  = (const float*)d_in[4];
  const float* Wl2 = (const float*)d_in[5];
  const float* Wr2 = (const float*)d_in[6];
  const float* b2  = (const float*)d_in[7];
  const float* Wl3 = (const float*)d_in[8];
  const float* Wr3 = (const float*)d_in[9];
  const float* b3  = (const float*)d_in[10];

  char* ws = (char*)d_ws;
  size_t o = 0;
  auto alloc = [&](size_t bytes) -> void* {
    void* p = ws + o;
    o += (bytes + 255) & ~(size_t)255;
    return p;
  };
  int*   deg    = (int*)  alloc(N_NODES * 4);
  int*   off    = (int*)  alloc(N_NODES * 4);
  float* invdeg = (float*)alloc(N_NODES * 4);
  int*   bpart  = (int*)  alloc((size_t)AB * NBKT * 4);
  int*   bbase  = (int*)  alloc((NBKT + 1) * 4);
  int*   bcur   = (int*)  alloc(NBKT * 4);
  int2*  pairs  = (int2*) alloc((size_t)N_EDGES * 8);
  int*   cols   = (int*)  alloc(N_EDGES * 4);
  u16*   Xb     = (u16*)  alloc((size_t)N_NODES * 128 * 2);
  u16*   XRb    = (u16*)  alloc((size_t)N_NODES * 128 * 2);
  u16*   XLb    = (u16*)  alloc((size_t)N_NODES * 128 * 2);
  u16*   WT1    = (u16*)  alloc(256 * 128 * 2);
  u16*   WT2    = (u16*)  alloc(256 * 128 * 2);
  u16*   WT3    = (u16*)  alloc(128 * 128 * 2);

  // 1. prep (cast + wprep x3) + A1 partial histograms
  k_prep_a1<<<CASTB + 320 + AB, 256, 0, stream>>>(x, Xb, Wl1, Wr1, Wl2, Wr2,
                                                  Wl3, Wr3, WT1, WT2, WT3,
                                                  edges, bpart);
  // 2. reduce + scan bucket counts
  k_scanb<<<1, 256, 0, stream>>>(bpart, bbase, bcur);
  // 3. bucket-major pair scatter
  kA2<<<AB, 256, 0, stream>>>(edges, bcur, pairs);
  // 4. bucket counting sort (CSR) + layer-1 GEMM (independent, fused)
  k_kb_gemm<<<NBKT + MG, 256, 0, stream>>>(pairs, bbase, off, deg, invdeg, cols,
                                           Xb, WT1, b1, XLb, XRb);
  // 5. layer-1 aggregate
  k_agg128<true><<<N_NODES / 16, 256, 0, stream>>>(off, deg, invdeg, cols, XLb, XRb, (uint4*)Xb);
  // 6/7. layer 2
  k_gemm<<<MG, 256, 0, stream>>>(Xb, WT2, b2, XLb, XRb, 128);
  k_agg128<true><<<N_NODES / 16, 256, 0, stream>>>(off, deg, invdeg, cols, XLb, XRb, (uint4*)Xb);
  // 8/9. layer 3 (output fp32)
  k_gemm<<<MG, 256, 0, stream>>>(Xb, WT3, b3, XLb, XRb, 64);
  k_agg64<<<(N_NODES + 31) / 32, 256, 0, stream>>>(off, deg, invdeg, cols, XLb, XRb, (float*)d_out);
}

// Round 7
// 234.857 us; speedup vs baseline: 2.0658x; 1.0501x over previous
//
#include <hip/hip_runtime.h>
#include <hip/hip_bf16.h>

#define N_NODES 50000
#define N_EDGES 800000
#define NBKT 196           // ceil(50000/256) buckets of 256 nodes
#define ACHUNK 4096        // edges per block in binning kernels
#define AB 196             // ceil(800000/4096) histogram blocks
#define CASTB 6250         // 50000*128/4 float4 chunks / 256 threads
#define MG 782             // ceil(50000/64) gemm row-tiles

typedef unsigned short u16;
typedef short v8s __attribute__((ext_vector_type(8)));
typedef float v4f __attribute__((ext_vector_type(4)));

__device__ __forceinline__ u16 f2bf(float f){
  union { float f; unsigned u; } x; x.f = f;
  unsigned u = x.u;
  return (u16)((u + 0x7FFFu + ((u >> 16) & 1u)) >> 16);   // RNE
}
__device__ __forceinline__ float lo_bf(unsigned u){
  union { unsigned u; float f; } x; x.u = u << 16; return x.f;
}
__device__ __forceinline__ float hi_bf(unsigned u){
  union { unsigned u; float f; } x; x.u = u & 0xffff0000u; return x.f;
}

// ---------------- fused prep: cast x->bf16, 3x weight transpose, A1 partial hists

__device__ __forceinline__ void wprep1(const float* __restrict__ Wl,
                                       const float* __restrict__ Wr,
                                       u16* __restrict__ WT, int N1, int idx){
  int n = idx >> 7, k = idx & 127;
  float v = (n < N1) ? Wl[k * N1 + n] : Wr[k * N1 + (n - N1)];
  WT[n * 128 + k] = f2bf(v);
}

__global__ __launch_bounds__(256) void k_prep_a1(const float* __restrict__ x,
                                                 u16* __restrict__ Xb,
                                                 const float* __restrict__ Wl1,
                                                 const float* __restrict__ Wr1,
                                                 const float* __restrict__ Wl2,
                                                 const float* __restrict__ Wr2,
                                                 const float* __restrict__ Wl3,
                                                 const float* __restrict__ Wr3,
                                                 u16* __restrict__ WT1,
                                                 u16* __restrict__ WT2,
                                                 u16* __restrict__ WT3,
                                                 const int* __restrict__ edges,
                                                 int* __restrict__ bpart){
  __shared__ int h[NBKT];
  int b = blockIdx.x, tid = threadIdx.x;
  if (b < CASTB){
    int i = b * 256 + tid;                       // exact: 6250*256 = 1.6M float4
    float4 v = ((const float4*)x)[i];
    ((ushort4*)Xb)[i] = make_ushort4(f2bf(v.x), f2bf(v.y), f2bf(v.z), f2bf(v.w));
  } else if (b < CASTB + 128){
    wprep1(Wl1, Wr1, WT1, 128, (b - CASTB) * 256 + tid);
  } else if (b < CASTB + 256){
    wprep1(Wl2, Wr2, WT2, 128, (b - CASTB - 128) * 256 + tid);
  } else if (b < CASTB + 320){
    wprep1(Wl3, Wr3, WT3, 64, (b - CASTB - 256) * 256 + tid);   // 64 blocks
  } else {
    int ab = b - (CASTB + 320);                  // 0..AB-1
    for (int i = tid; i < NBKT; i += 256) h[i] = 0;
    __syncthreads();
    int base = ab * ACHUNK;
    for (int i = tid; i < ACHUNK; i += 256){
      int j = base + i;
      if (j < N_EDGES) atomicAdd(&h[edges[N_EDGES + j] >> 8], 1);
    }
    __syncthreads();
    for (int i = tid; i < NBKT; i += 256) bpart[ab * NBKT + i] = h[i];
  }
}

// reduce partial hists + scan -> bbase (exclusive, +total), init bcur
__global__ __launch_bounds__(256) void k_scanb(const int* __restrict__ bpart,
                                               int* __restrict__ bbase,
                                               int* __restrict__ bcur){
  __shared__ int s[256];
  int tid = threadIdx.x;
  int v = 0;
  if (tid < NBKT){
    int a0 = 0, a1 = 0, a2 = 0, a3 = 0;
    int r = 0;
    for (; r + 4 <= AB; r += 4){
      a0 += bpart[(r    ) * NBKT + tid];
      a1 += bpart[(r + 1) * NBKT + tid];
      a2 += bpart[(r + 2) * NBKT + tid];
      a3 += bpart[(r + 3) * NBKT + tid];
    }
    for (; r < AB; ++r) a0 += bpart[r * NBKT + tid];
    v = (a0 + a1) + (a2 + a3);
  }
  s[tid] = v; __syncthreads();
  for (int d = 1; d < 256; d <<= 1){
    int t = (tid >= d) ? s[tid - d] : 0;
    __syncthreads();
    s[tid] += t;
    __syncthreads();
  }
  if (tid < NBKT){ bbase[tid] = s[tid] - v; bcur[tid] = s[tid] - v; }
  if (tid == NBKT - 1) bbase[NBKT] = s[tid];
}

// bucket-major scatter; pair packed as (src<<8) | (dst & 255)  (src<2^17 fits)
__global__ __launch_bounds__(256) void kA2(const int* __restrict__ edges,
                                           int* __restrict__ bcur,
                                           unsigned* __restrict__ pairs){
  __shared__ int h[NBKT];
  int tid = threadIdx.x;
  for (int i = tid; i < NBKT; i += 256) h[i] = 0;
  __syncthreads();
  int base = blockIdx.x * ACHUNK;
  for (int i = tid; i < ACHUNK; i += 256){
    int j = base + i;
    if (j < N_EDGES) atomicAdd(&h[edges[N_EDGES + j] >> 8], 1);
  }
  __syncthreads();
  for (int i = tid; i < NBKT; i += 256)
    h[i] = h[i] ? atomicAdd(&bcur[i], h[i]) : 0;   // h becomes block-local cursor
  __syncthreads();
  for (int i = tid; i < ACHUNK; i += 256){
    int j = base + i;
    if (j < N_EDGES){
      int s = edges[j], d = edges[N_EDGES + j];
      int pos = atomicAdd(&h[d >> 8], 1);
      pairs[pos] = ((unsigned)s << 8) | (unsigned)(d & 255);
    }
  }
}

// ---------------- kB body (bucket counting sort) --------------------

__device__ __forceinline__ void kB_body(int bkt, int tid,
                                        const unsigned* __restrict__ pairs,
                                        const int* __restrict__ bbase,
                                        int* __restrict__ off,
                                        int* __restrict__ deg,
                                        float* __restrict__ invdeg,
                                        int* __restrict__ cols,
                                        int* h, int* s, int* cur){
  int base = bbase[bkt], cnt = bbase[bkt + 1] - base;
  int nodeBase = bkt << 8;

  h[tid] = 0; __syncthreads();
  for (int i = tid; i < cnt; i += 256){
    unsigned p = pairs[base + i];
    atomicAdd(&h[p & 255u], 1);
  }
  __syncthreads();
  int v = h[tid];
  s[tid] = v; __syncthreads();
  for (int d = 1; d < 256; d <<= 1){
    int t = (tid >= d) ? s[tid - d] : 0;
    __syncthreads();
    s[tid] += t;
    __syncthreads();
  }
  int excl = s[tid] - v;
  int node = nodeBase + tid;
  if (node < N_NODES){
    off[node] = base + excl;
    deg[node] = v;
    invdeg[node] = 1.0f / (float)(v > 1 ? v : 1);
  }
  cur[tid] = base + excl;
  __syncthreads();
  for (int i = tid; i < cnt; i += 256){
    unsigned p = pairs[base + i];
    int pos = atomicAdd(&cur[p & 255u], 1);
    cols[pos] = (int)(p >> 8);
  }
}

// ---------------- GEMM inner: assumes As staged; runs col phases ---------------
// XLb = bf16(A@Wl + b), XR = bf16(A@Wr). WT rows [0,N1)=Wl^T, [N1,2N1)=Wr^T.

__device__ __forceinline__ void gemm_inner(int rowBase, int tid,
                                           const u16* __restrict__ WT,
                                           const float* __restrict__ bias,
                                           u16* __restrict__ XLb,
                                           u16* __restrict__ XR, int N1,
                                           u16* As, u16* Bs){
  const int lane = tid & 63, wave = tid >> 6;
  const int quad = lane >> 4, l15 = lane & 15;
  const int wm = wave & 1, wn = wave >> 1;
  const int nph = N1 >> 5;                       // (2*N1)/64 phases

  for (int p = 0; p < nph; ++p){
    int colBase = p * 64;
    #pragma unroll
    for (int it = 0; it < 4; ++it){
      int chunk = tid + it * 256;
      int r = chunk >> 4, cseg = chunk & 15;
      ((uint4*)Bs)[r * 17 + cseg] = ((const uint4*)(WT + (size_t)(colBase + r) * 128))[cseg];
    }
    __syncthreads();

    v4f acc[2][2] = {};
    #pragma unroll
    for (int kt = 0; kt < 4; ++kt){
      int ko = kt * 32 + quad * 8;
      v8s a0 = *(const v8s*)&As[(wm * 32 + l15) * 136 + ko];
      v8s a1 = *(const v8s*)&As[(wm * 32 + 16 + l15) * 136 + ko];
      v8s b0 = *(const v8s*)&Bs[(wn * 32 + l15) * 136 + ko];
      v8s b1 = *(const v8s*)&Bs[(wn * 32 + 16 + l15) * 136 + ko];
      acc[0][0] = __builtin_amdgcn_mfma_f32_16x16x32_bf16(a0, b0, acc[0][0], 0, 0, 0);
      acc[0][1] = __builtin_amdgcn_mfma_f32_16x16x32_bf16(a0, b1, acc[0][1], 0, 0, 0);
      acc[1][0] = __builtin_amdgcn_mfma_f32_16x16x32_bf16(a1, b0, acc[1][0], 0, 0, 0);
      acc[1][1] = __builtin_amdgcn_mfma_f32_16x16x32_bf16(a1, b1, acc[1][1], 0, 0, 0);
    }

    #pragma unroll
    for (int mi = 0; mi < 2; ++mi)
      #pragma unroll
      for (int ni = 0; ni < 2; ++ni)
        #pragma unroll
        for (int r = 0; r < 4; ++r){
          int grow = rowBase + wm * 32 + mi * 16 + quad * 4 + r;
          int gcol = colBase + wn * 32 + ni * 16 + l15;
          if (grow < N_NODES){
            float v = acc[mi][ni][r];
            if (gcol < N1) XLb[(size_t)grow * N1 + gcol] = f2bf(v + bias[gcol]);
            else           XR[(size_t)grow * N1 + (gcol - N1)] = f2bf(v);
          }
        }
    __syncthreads();
  }
}

__device__ __forceinline__ void gemm_body(int blk, int tid,
                                          const u16* __restrict__ A,
                                          const u16* __restrict__ WT,
                                          const float* __restrict__ bias,
                                          u16* __restrict__ XLb,
                                          u16* __restrict__ XR, int N1,
                                          u16* As, u16* Bs){
  const int rowBase = blk * 64;
  #pragma unroll
  for (int it = 0; it < 4; ++it){
    int chunk = tid + it * 256;
    int r = chunk >> 4, cseg = chunk & 15;
    int gr = rowBase + r;
    uint4 va = make_uint4(0u, 0u, 0u, 0u);
    if (gr < N_NODES) va = ((const uint4*)(A + (size_t)gr * 128))[cseg];
    ((uint4*)As)[r * 17 + cseg] = va;
  }
  gemm_inner(rowBase, tid, WT, bias, XLb, XR, N1, As, Bs);
}

// kernel 4: bucket counting sort (blocks 0..NBKT) + layer-1 GEMM (rest)
__global__ __launch_bounds__(256) void k_kb_gemm(const unsigned* __restrict__ pairs,
                                                 const int* __restrict__ bbase,
                                                 int* __restrict__ off,
                                                 int* __restrict__ deg,
                                                 float* __restrict__ invdeg,
                                                 int* __restrict__ cols,
                                                 const u16* __restrict__ A,
                                                 const u16* __restrict__ WT,
                                                 const float* __restrict__ bias,
                                                 u16* __restrict__ XLb,
                                                 u16* __restrict__ XR){
  __shared__ u16 As[64 * 136];
  __shared__ u16 Bs[64 * 136];
  int tid = threadIdx.x;
  if (blockIdx.x < NBKT){
    int* h = (int*)As;                 // 3 KB aliased into As
    kB_body(blockIdx.x, tid, pairs, bbase, off, deg, invdeg, cols,
            h, h + 256, h + 512);
  } else {
    gemm_body(blockIdx.x - NBKT, tid, A, WT, bias, XLb, XR, 128, As, Bs);
  }
}

// ---------------- per-node aggregate (128-wide, relu, bf16 out as uint4) -------

__device__ __forceinline__ uint4 agg_node128(int node, int f,
                                             const int* __restrict__ off,
                                             const int* __restrict__ deg,
                                             const float* __restrict__ invdeg,
                                             const int* __restrict__ cols,
                                             const u16* __restrict__ XLb,
                                             const u16* __restrict__ XR){
  int start = off[node], cnt = deg[node];
  float inv = invdeg[node];
  const uint4* __restrict__ XR4 = (const uint4*)XR;   // row = 16 uint4
  const int* __restrict__ cb = cols + start;

  float2 a0 = make_float2(0.f, 0.f), a1 = a0, a2 = a0, a3 = a0;
  auto accum = [&](uint4 u){
    a0.x += lo_bf(u.x); a0.y += hi_bf(u.x);
    a1.x += lo_bf(u.y); a1.y += hi_bf(u.y);
    a2.x += lo_bf(u.z); a2.y += hi_bf(u.z);
    a3.x += lo_bf(u.w); a3.y += hi_bf(u.w);
  };

  int e = 0;
  int nfull = cnt & ~7;
  for (; e < nfull; e += 8){
    int s[8];
    #pragma unroll
    for (int j = 0; j < 8; ++j) s[j] = cb[e + j];
    uint4 u[8];
    #pragma unroll
    for (int j = 0; j < 8; ++j) u[j] = XR4[(size_t)s[j] * 16 + f];
    #pragma unroll
    for (int j = 0; j < 8; ++j) accum(u[j]);
  }
  if (e < cnt){                                 // masked 8-granule tail (<=1 iter)
    int last = cnt - 1;
    int s[8];
    #pragma unroll
    for (int j = 0; j < 8; ++j){
      int i = e + j;
      s[j] = cb[i < last ? i : last];
    }
    uint4 u[8];
    #pragma unroll
    for (int j = 0; j < 8; ++j) u[j] = XR4[(size_t)s[j] * 16 + f];
    #pragma unroll
    for (int j = 0; j < 8; ++j){
      if (e + j > last) u[j] = make_uint4(0u, 0u, 0u, 0u);
      accum(u[j]);
    }
  }

  uint4 xl = ((const uint4*)XLb)[(size_t)node * 16 + f];
  float o0 = lo_bf(xl.x) + inv * a0.x, o1 = hi_bf(xl.x) + inv * a0.y;
  float o2 = lo_bf(xl.y) + inv * a1.x, o3 = hi_bf(xl.y) + inv * a1.y;
  float o4 = lo_bf(xl.z) + inv * a2.x, o5 = hi_bf(xl.z) + inv * a2.y;
  float o6 = lo_bf(xl.w) + inv * a3.x, o7 = hi_bf(xl.w) + inv * a3.y;
  o0 = fmaxf(o0, 0.f); o1 = fmaxf(o1, 0.f); o2 = fmaxf(o2, 0.f); o3 = fmaxf(o3, 0.f);
  o4 = fmaxf(o4, 0.f); o5 = fmaxf(o5, 0.f); o6 = fmaxf(o6, 0.f); o7 = fmaxf(o7, 0.f);
  uint4 ov;
  ov.x = (unsigned)f2bf(o0) | ((unsigned)f2bf(o1) << 16);
  ov.y = (unsigned)f2bf(o2) | ((unsigned)f2bf(o3) << 16);
  ov.z = (unsigned)f2bf(o4) | ((unsigned)f2bf(o5) << 16);
  ov.w = (unsigned)f2bf(o6) | ((unsigned)f2bf(o7) << 16);
  return ov;
}

// ---------------- fused agg(layer l) + GEMM(layer l+1) -------------------------
// Block aggregates its 64 nodes into the As LDS tile (h never hits global),
// then runs the next layer's GEMM phases on it.

__global__ __launch_bounds__(256) void k_aggemm(const int* __restrict__ off,
                                                const int* __restrict__ deg,
                                                const float* __restrict__ invdeg,
                                                const int* __restrict__ cols,
                                                const u16* __restrict__ XLb_in,
                                                const u16* __restrict__ XR_in,
                                                const u16* __restrict__ WT,
                                                const float* __restrict__ bias,
                                                u16* __restrict__ XLb_out,
                                                u16* __restrict__ XR_out,
                                                int N1_out){
  __shared__ u16 As[64 * 136];
  __shared__ u16 Bs[64 * 136];
  int tid = threadIdx.x;
  int qq = tid >> 4, f = tid & 15;
  int rowBase = blockIdx.x * 64;

  #pragma unroll
  for (int pass = 0; pass < 4; ++pass){
    int lr = pass * 16 + qq;                    // local row 0..63
    int node = rowBase + lr;
    uint4 ov = make_uint4(0u, 0u, 0u, 0u);
    if (node < N_NODES)
      ov = agg_node128(node, f, off, deg, invdeg, cols, XLb_in, XR_in);
    ((uint4*)As)[lr * 17 + f] = ov;
  }
  // barrier before MFMA reads As is provided inside gemm_inner (post-B-stage sync)
  gemm_inner(rowBase, tid, WT, bias, XLb_out, XR_out, N1_out, As, Bs);
}

// ---------------- final aggregate (64-wide, fp32 out) --------------------------
__global__ __launch_bounds__(256) void k_agg64(const int* __restrict__ off,
                                               const int* __restrict__ deg,
                                               const float* __restrict__ invdeg,
                                               const int* __restrict__ cols,
                                               const u16* __restrict__ XLb,
                                               const u16* __restrict__ XR,
                                               float* __restrict__ out){
  int tid = threadIdx.x;
  int oo = tid >> 3, f = tid & 7;
  int node = blockIdx.x * 32 + oo;
  if (node >= N_NODES) return;
  int start = off[node], cnt = deg[node];
  float inv = invdeg[node];
  const uint4* __restrict__ XR4 = (const uint4*)XR;   // row = 8 uint4
  const int* __restrict__ cb = cols + start;

  float2 a0 = make_float2(0.f, 0.f), a1 = a0, a2 = a0, a3 = a0;
  auto accum = [&](uint4 u){
    a0.x += lo_bf(u.x); a0.y += hi_bf(u.x);
    a1.x += lo_bf(u.y); a1.y += hi_bf(u.y);
    a2.x += lo_bf(u.z); a2.y += hi_bf(u.z);
    a3.x += lo_bf(u.w); a3.y += hi_bf(u.w);
  };

  int e = 0;
  int nfull = cnt & ~7;
  for (; e < nfull; e += 8){
    int s[8];
    #pragma unroll
    for (int j = 0; j < 8; ++j) s[j] = cb[e + j];
    uint4 u[8];
    #pragma unroll
    for (int j = 0; j < 8; ++j) u[j] = XR4[(size_t)s[j] * 8 + f];
    #pragma unroll
    for (int j = 0; j < 8; ++j) accum(u[j]);
  }
  if (e < cnt){
    int last = cnt - 1;
    int s[8];
    #pragma unroll
    for (int j = 0; j < 8; ++j){
      int i = e + j;
      s[j] = cb[i < last ? i : last];
    }
    uint4 u[8];
    #pragma unroll
    for (int j = 0; j < 8; ++j) u[j] = XR4[(size_t)s[j] * 8 + f];
    #pragma unroll
    for (int j = 0; j < 8; ++j){
      if (e + j > last) u[j] = make_uint4(0u, 0u, 0u, 0u);
      accum(u[j]);
    }
  }

  uint4 xl = ((const uint4*)XLb)[(size_t)node * 8 + f];
  float4 oa, ob;
  oa.x = lo_bf(xl.x) + inv * a0.x; oa.y = hi_bf(xl.x) + inv * a0.y;
  oa.z = lo_bf(xl.y) + inv * a1.x; oa.w = hi_bf(xl.y) + inv * a1.y;
  ob.x = lo_bf(xl.z) + inv * a2.x; ob.y = hi_bf(xl.z) + inv * a2.y;
  ob.z = lo_bf(xl.w) + inv * a3.x; ob.w = hi_bf(xl.w) + inv * a3.y;
  ((float4*)out)[(size_t)node * 16 + 2 * f]     = oa;
  ((float4*)out)[(size_t)node * 16 + 2 * f + 1] = ob;
}

// ---------------- launch ----------------

extern "C" void kernel_launch(void* const* d_in, const int* in_sizes, int n_in,
                              void* d_out, int out_size, void* d_ws, size_t ws_size,
                              hipStream_t stream) {
  const float* x     = (const float*)d_in[0];
  const int*   edges = (const int*)  d_in[1];
  const float* Wl1 = (const float*)d_in[2];
  const float* Wr1 = (const float*)d_in[3];
  const float* b1  = (const float*)d_in[4];
  const float* Wl2 = (const float*)d_in[5];
  const float* Wr2 = (const float*)d_in[6];
  const float* b2  = (const float*)d_in[7];
  const float* Wl3 = (const float*)d_in[8];
  const float* Wr3 = (const float*)d_in[9];
  const float* b3  = (const float*)d_in[10];

  char* ws = (char*)d_ws;
  size_t o = 0;
  auto alloc = [&](size_t bytes) -> void* {
    void* p = ws + o;
    o += (bytes + 255) & ~(size_t)255;
    return p;
  };
  int*      deg    = (int*)     alloc(N_NODES * 4);
  int*      off    = (int*)     alloc(N_NODES * 4);
  float*    invdeg = (float*)   alloc(N_NODES * 4);
  int*      bpart  = (int*)     alloc((size_t)AB * NBKT * 4);
  int*      bbase  = (int*)     alloc((NBKT + 1) * 4);
  int*      bcur   = (int*)     alloc(NBKT * 4);
  unsigned* pairs  = (unsigned*)alloc((size_t)N_EDGES * 4);
  int*      cols   = (int*)     alloc(N_EDGES * 4);
  u16*      Xb     = (u16*)     alloc((size_t)N_NODES * 128 * 2);
  u16*      XLbA   = (u16*)     alloc((size_t)N_NODES * 128 * 2);
  u16*      XRbA   = (u16*)     alloc((size_t)N_NODES * 128 * 2);
  u16*      XLbB   = (u16*)     alloc((size_t)N_NODES * 128 * 2);
  u16*      XRbB   = (u16*)     alloc((size_t)N_NODES * 128 * 2);
  u16*      WT1    = (u16*)     alloc(256 * 128 * 2);
  u16*      WT2    = (u16*)     alloc(256 * 128 * 2);
  u16*      WT3    = (u16*)     alloc(128 * 128 * 2);

  // 1. prep (cast + wprep x3) + A1 partial histograms
  k_prep_a1<<<CASTB + 320 + AB, 256, 0, stream>>>(x, Xb, Wl1, Wr1, Wl2, Wr2,
                                                  Wl3, Wr3, WT1, WT2, WT3,
                                                  edges, bpart);
  // 2. reduce + scan bucket counts
  k_scanb<<<1, 256, 0, stream>>>(bpart, bbase, bcur);
  // 3. bucket-major pair scatter (packed u32 pairs)
  kA2<<<AB, 256, 0, stream>>>(edges, bcur, pairs);
  // 4. bucket counting sort (CSR) + layer-1 GEMM (independent, fused)
  k_kb_gemm<<<NBKT + MG, 256, 0, stream>>>(pairs, bbase, off, deg, invdeg, cols,
                                           Xb, WT1, b1, XLbA, XRbA);
  // 5. agg1 + gemm2 fused (h1 lives only in LDS)
  k_aggemm<<<MG, 256, 0, stream>>>(off, deg, invdeg, cols, XLbA, XRbA,
                                   WT2, b2, XLbB, XRbB, 128);
  // 6. agg2 + gemm3 fused
  k_aggemm<<<MG, 256, 0, stream>>>(off, deg, invdeg, cols, XLbB, XRbB,
                                   WT3, b3, XLbA, XRbA, 64);
  // 7. final aggregate (fp32 out)
  k_agg64<<<(N_NODES + 31) / 32, 256, 0, stream>>>(off, deg, invdeg, cols,
                                                   XLbA, XRbA, (float*)d_out);
}